// Round 7
// baseline (10042.995 us; speedup 1.0000x reference)
//
#include <hip/hip_runtime.h>
#include <hip/hip_cooperative_groups.h>

static constexpr int Bc = 128;   // batch
static constexpr int Tc = 256;   // timesteps
static constexpr int Ec = 512;   // input embed
static constexpr int Hc = 1024;  // hidden

using bf16x8 = __attribute__((ext_vector_type(8))) short;
using f32x4  = __attribute__((ext_vector_type(4))) float;

__device__ __forceinline__ unsigned short f2bf(float f) {
  unsigned int u = __float_as_uint(f);
  u += 0x7FFFu + ((u >> 16) & 1u);
  return (unsigned short)(u >> 16);
}
__device__ __forceinline__ float sigm(float x) { return 1.0f / (1.0f + __expf(-x)); }

#define MFMA16(A, Bf, C) __builtin_amdgcn_mfma_f32_16x16x32_bf16((A), (Bf), (C), 0, 0, 0)

// ---- fence-free L3-coherent primitives (no wbl2/inv ever) ----
// single-thread relaxed agent poll with sleep backoff (L3-direct, no maintenance)
__device__ __forceinline__ void poll_rlx(const int* p, int tgt) {
  while (__hip_atomic_load(p, __ATOMIC_RELAXED, __HIP_MEMORY_SCOPE_AGENT) < tgt)
    __builtin_amdgcn_s_sleep(2);
}
// relaxed agent-scope increment (ordering provided by pre-barrier vmcnt(0) drain)
__device__ __forceinline__ void sig_add(int* p) {
  __hip_atomic_fetch_add(p, 1, __ATOMIC_RELAXED, __HIP_MEMORY_SCOPE_AGENT);
}
// L3-coherent 16B fragment load as 2x8B agent-relaxed loads (bypass stale L2)
__device__ __forceinline__ bf16x8 ldg_c(const unsigned short* p) {
  union { unsigned long long u[2]; bf16x8 v; } r;
  r.u[0] = __hip_atomic_load((const unsigned long long*)p,       __ATOMIC_RELAXED, __HIP_MEMORY_SCOPE_AGENT);
  r.u[1] = __hip_atomic_load((const unsigned long long*)(p + 4), __ATOMIC_RELAXED, __HIP_MEMORY_SCOPE_AGENT);
  return r.v;
}
// L3-coherent 2B store (write-through: lands at coherence point, no dirty L2)
__device__ __forceinline__ void stg_c(unsigned short* p, unsigned short v) {
  __hip_atomic_store(p, v, __ATOMIC_RELAXED, __HIP_MEMORY_SCOPE_AGENT);
}

// ----------------- prep kernels -----------------
__global__ void k_cvt_bf16(const float* __restrict__ src, unsigned short* __restrict__ dst, int n) {
  int i = (blockIdx.x * blockDim.x + threadIdx.x) * 4;
  if (i + 3 < n) {
    f32x4 v = *(const f32x4*)(src + i);
    *(ushort4*)(dst + i) = make_ushort4(f2bf(v[0]), f2bf(v[1]), f2bf(v[2]), f2bf(v[3]));
  }
}

__global__ void k_prep_small(const float* __restrict__ bih0, const float* __restrict__ bhh0,
                             float* __restrict__ b0s,
                             unsigned short* __restrict__ h1buf, unsigned short* __restrict__ h2buf,
                             int* __restrict__ d1, int* __restrict__ d2) {
  int i = blockIdx.x * blockDim.x + threadIdx.x;  // grid covers 4*Bc*Hc = 524288
  if (i < 4096) b0s[i] = bih0[i] + bhh0[i];
  h1buf[i] = 0; h2buf[i] = 0;
  if (i < Tc * 16) { d1[i] = 0; d2[i] = 0; }      // per-phase counter lines (64B stride)
}

// ----------------- layer-0 bulk GEMM (no recurrence; f-gate dead) -----------------
__global__ __launch_bounds__(512, 1) void k_l0(
    const unsigned short* __restrict__ xb, const unsigned short* __restrict__ W0,
    const float* __restrict__ b0s, unsigned short* __restrict__ H0)
{
  const int tid = threadIdx.x;
  const int lane = tid & 63, wid = tid >> 6;
  const int wM = wid >> 2, wN = wid & 3;           // 8 waves: 2(M) x 4(N)
  const int rowbase = blockIdx.x * 32 + wM * 16;
  const int jbase   = blockIdx.y * 64 + wN * 16;
  const int ri = lane & 15, kg = lane >> 4;

  const int r = rowbase + ri;
  const int t = r >> 7, b = r & (Bc - 1);
  const unsigned short* arow = xb + ((size_t)b * Tc + t) * Ec + kg * 8;

  const unsigned short* w0r = W0 + ((size_t)(0 * Hc + jbase + ri)) * Ec + kg * 8;
  const unsigned short* w2r = W0 + ((size_t)(2 * Hc + jbase + ri)) * Ec + kg * 8;
  const unsigned short* w3r = W0 + ((size_t)(3 * Hc + jbase + ri)) * Ec + kg * 8;

  f32x4 ai = {0,0,0,0}, ag = {0,0,0,0}, ao = {0,0,0,0};
#pragma unroll
  for (int kk = 0; kk < Ec / 32; ++kk) {
    bf16x8 a = *(const bf16x8*)(arow + kk * 32);
    ai = MFMA16(a, *(const bf16x8*)(w0r + kk * 32), ai);
    ag = MFMA16(a, *(const bf16x8*)(w2r + kk * 32), ag);
    ao = MFMA16(a, *(const bf16x8*)(w3r + kk * 32), ao);
  }
  const int j = jbase + ri;
  const float bi = b0s[j], bg = b0s[2 * Hc + j], bo = b0s[3 * Hc + j];
#pragma unroll
  for (int q = 0; q < 4; ++q) {
    const int rr = rowbase + kg * 4 + q;
    float c = sigm(ai[q] + bi) * tanhf(ag[q] + bg);
    float h = sigm(ao[q] + bo) * tanhf(c);
    H0[(size_t)rr * Hc + j] = f2bf(h);
  }
}

// ----------------- recurrent kernel: round-6 compute + low-traffic counter sync -----------
// 256 WGs x 512 thr (8 waves), 1 WG/CU. WGs 0..127: layer1; 128..255: layer2.
// h-state accessed ONLY with agent-scope relaxed ops -> served at L3; no cache
// maintenance anywhere. Per-phase completion counters d1[p], d2[s] (own 64B line):
// producer = pre-barrier vmcnt(0) store drain -> tid0 relaxed fetch_add; consumer =
// tid0 relaxed poll >=128 -> __syncthreads. <=256 concurrent pollers chip-wide.
__global__ __launch_bounds__(512, 1) void k_rec(
    const unsigned short* H0,                        // [Tc*Bc][Hc] bf16 (upper half of d_out)
    const float* __restrict__ Wih, const float* __restrict__ Whh,  // [2][4096][1024] f32
    const float* __restrict__ bih, const float* __restrict__ bhh,  // [2][4096] f32
    unsigned short* h1buf, unsigned short* h2buf,    // [4][Bc][Hc] bf16
    int* d1, int* d2,                                // [Tc] counters, 64B stride (16 ints)
    float* out)                                      // [Tc][Bc][Hc] f32 (lower d_out)
{
  __shared__ unsigned short Wlds[2 * 64 * 64 * 8];   // 128 KiB: [tile][kstep][lane][8]
  const int tid = threadIdx.x;
  const int lane = tid & 63, wid = tid >> 6;
  const int bid = blockIdx.x;
  const int layer = bid >> 7;
  const int w = bid & 127;
  const int j0 = w * 8;
  const int ri = lane & 15, kg = lane >> 4;

  // ---- prologue: weights fp32 -> bf16 into LDS, fragment-major ----
  const size_t lw = (size_t)layer * 4096 * 1024;
  for (int s = tid; s < 2 * 64 * 64; s += 512) {
    const int l   = s & 63;
    const int kkg = (s >> 6) & 63;
    const int t   = s >> 12;
    const int rr  = l & 15;
    const int gate = t * 2 + (rr >> 3);
    const int R = gate * 1024 + j0 + (rr & 7);
    const int k = kkg * 32 + (l >> 4) * 8;
    const float* src = (k < 1024) ? (Wih + lw + (size_t)R * 1024 + k)
                                  : (Whh + lw + (size_t)R * 1024 + (k - 1024));
    f32x4 v0 = *(const f32x4*)src;
    f32x4 v1 = *(const f32x4*)(src + 4);
    ushort4* d = (ushort4*)(Wlds + (size_t)s * 8);
    d[0] = make_ushort4(f2bf(v0[0]), f2bf(v0[1]), f2bf(v0[2]), f2bf(v0[3]));
    d[1] = make_ushort4(f2bf(v1[0]), f2bf(v1[1]), f2bf(v1[2]), f2bf(v1[3]));
  }

  const int jme = j0 + (ri & 7);
  const int g0 = (ri < 8) ? 0 : 1;                  // tile0: i | f
  const int g1 = (ri < 8) ? 2 : 3;                  // tile1: g | o
  const float bias0 = bih[layer * 4096 + g0 * 1024 + jme] + bhh[layer * 4096 + g0 * 1024 + jme];
  const float bias1 = bih[layer * 4096 + g1 * 1024 + jme] + bhh[layer * 4096 + g1 * 1024 + jme];

  float creg[4] = {0.f, 0.f, 0.f, 0.f};

  const unsigned short* lds0 = Wlds + (size_t)lane * 8;
  const unsigned short* lds1 = Wlds + (size_t)64 * 64 * 8 + (size_t)lane * 8;
  const int arow = wid * 16 + ri;
  const bool lo = (ri < 8);

  __syncthreads();                                  // Wlds ready

  if (layer == 0) {
    // ---------------- layer 1: h1(p) = cell(H0(p), h1(p-1)) ----------------
    for (int p = 0; p < Tc; ++p) {
      // free half: A1 = H0(p), K 0..1023 (no dependency; normal cached loads)
      const unsigned short* a1 = H0 + (size_t)p * Bc * Hc + (size_t)arow * Hc + kg * 8;
      f32x4 acc0 = {0,0,0,0}, acc1 = {0,0,0,0};
#pragma unroll
      for (int kk = 0; kk < 32; ++kk) {
        bf16x8 a = *(const bf16x8*)(a1 + kk * 32);
        acc0 = MFMA16(a, *(const bf16x8*)(lds0 + kk * 512), acc0);
        acc1 = MFMA16(a, *(const bf16x8*)(lds1 + kk * 512), acc1);
      }
      // gated half: wait h1(p-1) ready (all 128 producers), then L3-coherent loads
      if (tid == 0 && p >= 1) poll_rlx(d1 + (size_t)(p - 1) * 16, 128);
      __syncthreads();
      const unsigned short* a2 = h1buf + (size_t)((p - 1) & 3) * Bc * Hc + (size_t)arow * Hc + kg * 8;
#pragma unroll
      for (int kk = 32; kk < 64; ++kk) {
        bf16x8 a = ldg_c(a2 + (kk - 32) * 32);
        acc0 = MFMA16(a, *(const bf16x8*)(lds0 + kk * 512), acc0);
        acc1 = MFMA16(a, *(const bf16x8*)(lds1 + kk * 512), acc1);
      }
      // cell epilogue into registers
      float hn[4];
#pragma unroll
      for (int q = 0; q < 4; ++q) {
        float x0 = acc0[q] + bias0;
        float x1 = acc1[q] + bias1;
        float p0 = __shfl_xor(x0, 8);
        float p1 = __shfl_xor(x1, 8);
        float gi = lo ? x0 : p0;
        float gf = lo ? p0 : x0;
        float gg = lo ? x1 : p1;
        float go = lo ? p1 : x1;
        float cn = sigm(gf) * creg[q] + sigm(gi) * tanhf(gg);
        hn[q] = sigm(go) * tanhf(cn);
        creg[q] = cn;
      }
      // recycle wait: h1buf[p&3] last read by layer-2 step p-4
      if (tid == 0 && p >= 4) poll_rlx(d2 + (size_t)(p - 4) * 16, 128);
      __syncthreads();
      unsigned short* hb = h1buf + (size_t)(p & 3) * Bc * Hc;
      if (lo) {
#pragma unroll
        for (int q = 0; q < 4; ++q) {
          const int rr = wid * 16 + kg * 4 + q;
          stg_c(hb + (size_t)rr * Hc + jme, f2bf(hn[q]));
        }
      }
      __syncthreads();                              // pre-barrier vmcnt(0): stores ACKed at L3
      if (tid == 0) sig_add(d1 + (size_t)p * 16);
    }
  } else {
    // ---------------- layer 2: h2(s) = cell(h1(s), h2(s-1)) ----------------
    for (int s = 0; s < Tc; ++s) {
      // own-chain half first: wait h2(s-1)
      if (tid == 0 && s >= 1) poll_rlx(d2 + (size_t)(s - 1) * 16, 128);
      __syncthreads();
      const unsigned short* a2 = h2buf + (size_t)((s - 1) & 3) * Bc * Hc + (size_t)arow * Hc + kg * 8;
      f32x4 acc0 = {0,0,0,0}, acc1 = {0,0,0,0};
#pragma unroll
      for (int kk = 32; kk < 64; ++kk) {
        bf16x8 a = ldg_c(a2 + (kk - 32) * 32);
        acc0 = MFMA16(a, *(const bf16x8*)(lds0 + kk * 512), acc0);
        acc1 = MFMA16(a, *(const bf16x8*)(lds1 + kk * 512), acc1);
      }
      // cross-layer half: wait h1(s)
      if (tid == 0) poll_rlx(d1 + (size_t)s * 16, 128);
      __syncthreads();
      const unsigned short* a1 = h1buf + (size_t)(s & 3) * Bc * Hc + (size_t)arow * Hc + kg * 8;
#pragma unroll
      for (int kk = 0; kk < 32; ++kk) {
        bf16x8 a = ldg_c(a1 + kk * 32);
        acc0 = MFMA16(a, *(const bf16x8*)(lds0 + kk * 512), acc0);
        acc1 = MFMA16(a, *(const bf16x8*)(lds1 + kk * 512), acc1);
      }
      // cell epilogue + stores
      unsigned short* hb = h2buf + (size_t)(s & 3) * Bc * Hc;
      float* po = out + (size_t)s * Bc * Hc;
#pragma unroll
      for (int q = 0; q < 4; ++q) {
        float x0 = acc0[q] + bias0;
        float x1 = acc1[q] + bias1;
        float p0 = __shfl_xor(x0, 8);
        float p1 = __shfl_xor(x1, 8);
        float gi = lo ? x0 : p0;
        float gf = lo ? p0 : x0;
        float gg = lo ? x1 : p1;
        float go = lo ? p1 : x1;
        float cn = sigm(gf) * creg[q] + sigm(gi) * tanhf(gg);
        float hnv = sigm(go) * tanhf(cn);
        creg[q] = cn;
        const int rr = wid * 16 + kg * 4 + q;
        if (lo) {
          stg_c(hb + (size_t)rr * Hc + jme, f2bf(hnv));
          po[(size_t)rr * Hc + jme] = hnv;          // plain store; never read in-kernel
        }
      }
      __syncthreads();                              // pre-barrier vmcnt(0): stores ACKed at L3
      if (tid == 0) sig_add(d2 + (size_t)s * 16);
    }
  }
}

// ----------------- launcher -----------------
extern "C" void kernel_launch(void* const* d_in, const int* in_sizes, int n_in,
                              void* d_out, int out_size, void* d_ws, size_t ws_size,
                              hipStream_t stream) {
  const float* x     = (const float*)d_in[0];
  const float* W_ih0 = (const float*)d_in[1];
  // d_in[2] = W_hh0 (unused: layer-0 state is always zero)
  const float* b_ih0 = (const float*)d_in[3];
  const float* b_hh0 = (const float*)d_in[4];
  const float* W_ihr = (const float*)d_in[5];
  const float* W_hhr = (const float*)d_in[6];
  const float* b_ihr = (const float*)d_in[7];
  const float* b_hhr = (const float*)d_in[8];

  char* ws = (char*)d_ws;
  constexpr size_t W0B_OFF = 0;                                  // 4 MB
  constexpr size_t XB_OFF  = W0B_OFF + (size_t)4096 * 512 * 2;   // 32 MB
  constexpr size_t B0S_OFF = XB_OFF + (size_t)Bc * Tc * Ec * 2;  // 16 KB
  constexpr size_t H1B_OFF = B0S_OFF + 4096 * 4;                 // 1 MB
  constexpr size_t H2B_OFF = H1B_OFF + (size_t)4 * Bc * Hc * 2;  // 1 MB
  constexpr size_t D1_OFF  = H2B_OFF + (size_t)4 * Bc * Hc * 2;  // 16 KB (256 x 64B)
  constexpr size_t D2_OFF  = D1_OFF + (size_t)Tc * 16 * 4;       // 16 KB

  unsigned short* W0b = (unsigned short*)(ws + W0B_OFF);
  unsigned short* xb  = (unsigned short*)(ws + XB_OFF);
  float* b0s = (float*)(ws + B0S_OFF);
  unsigned short* h1buf = (unsigned short*)(ws + H1B_OFF);
  unsigned short* h2buf = (unsigned short*)(ws + H2B_OFF);
  int* d1 = (int*)(ws + D1_OFF);
  int* d2 = (int*)(ws + D2_OFF);

  // H0 (bf16 [T][B][H], 64 MB) lives in the upper half of d_out. out[s] (written at
  // layer-2 step s, after d1[s] >= 128) only overlaps H0[q] for q = 2(s-128)+{0,1} <= s,
  // i.e. strictly after layer 1 finished reading H0[q]. Verified byte-exact.
  unsigned short* H0 = (unsigned short*)d_out + (size_t)Tc * Bc * Hc;
  float* out = (float*)d_out;

  int n0 = 4096 * 512;
  k_cvt_bf16<<<n0 / 1024, 256, 0, stream>>>(W_ih0, W0b, n0);
  int nx = Bc * Tc * Ec;
  k_cvt_bf16<<<nx / 1024, 256, 0, stream>>>(x, xb, nx);
  k_prep_small<<<2048, 256, 0, stream>>>(b_ih0, b_hh0, b0s, h1buf, h2buf, d1, d2);
  k_l0<<<dim3(1024, 16), 512, 0, stream>>>(xb, W0b, b0s, H0);

  const float* Wih = W_ihr; const float* Whh = W_hhr;
  const float* bih = b_ihr; const float* bhh = b_hhr;
  void* kargs[] = { &H0, &Wih, &Whh, &bih, &bhh, &h1buf, &h2buf, &d1, &d2, &out };
  hipLaunchCooperativeKernel((void*)k_rec, dim3(256), dim3(512), kargs, 0, stream);
}

// Round 8
// 7019.969 us; speedup vs baseline: 1.4306x; 1.4306x over previous
//
#include <hip/hip_runtime.h>
#include <hip/hip_cooperative_groups.h>

static constexpr int Bc = 128;   // batch
static constexpr int Tc = 256;   // timesteps
static constexpr int Ec = 512;   // input embed
static constexpr int Hc = 1024;  // hidden
static constexpr int SLOT = Bc * Hc;  // one h-state tile (elems)

using bf16x8 = __attribute__((ext_vector_type(8))) short;
using f32x4  = __attribute__((ext_vector_type(4))) float;

__device__ __forceinline__ unsigned short f2bf(float f) {
  unsigned int u = __float_as_uint(f);
  u += 0x7FFFu + ((u >> 16) & 1u);
  return (unsigned short)(u >> 16);
}
__device__ __forceinline__ float sigm(float x) { return 1.0f / (1.0f + __expf(-x)); }

#define MFMA16(A, Bf, C) __builtin_amdgcn_mfma_f32_16x16x32_bf16((A), (Bf), (C), 0, 0, 0)

// ---- fence-free primitives (no wbl2/inv anywhere) ----
__device__ __forceinline__ void poll_rlx(const int* p, int tgt) {
  while (__hip_atomic_load(p, __ATOMIC_RELAXED, __HIP_MEMORY_SCOPE_AGENT) < tgt)
    __builtin_amdgcn_s_sleep(1);
}
__device__ __forceinline__ void sig(int* p, int v) {
  __hip_atomic_store(p, v, __ATOMIC_RELAXED, __HIP_MEMORY_SCOPE_AGENT);
}
// L3-coherent 16B load (sc1, bypasses possibly-stale L2) — used ONLY for h2 (4-deep, reused)
__device__ __forceinline__ bf16x8 ldg_c(const unsigned short* p) {
  union { unsigned long long u[2]; bf16x8 v; } r;
  r.u[0] = __hip_atomic_load((const unsigned long long*)p,       __ATOMIC_RELAXED, __HIP_MEMORY_SCOPE_AGENT);
  r.u[1] = __hip_atomic_load((const unsigned long long*)(p + 4), __ATOMIC_RELAXED, __HIP_MEMORY_SCOPE_AGENT);
  return r.v;
}
// L3 write-through 2B store: produced value lands at the coherence point pre-signal
__device__ __forceinline__ void stg_c(unsigned short* p, unsigned short v) {
  __hip_atomic_store(p, v, __ATOMIC_RELAXED, __HIP_MEMORY_SCOPE_AGENT);
}

// ----------------- prep kernels -----------------
__global__ void k_cvt_bf16(const float* __restrict__ src, unsigned short* __restrict__ dst, int n) {
  int i = (blockIdx.x * blockDim.x + threadIdx.x) * 4;
  if (i + 3 < n) {
    f32x4 v = *(const f32x4*)(src + i);
    *(ushort4*)(dst + i) = make_ushort4(f2bf(v[0]), f2bf(v[1]), f2bf(v[2]), f2bf(v[3]));
  }
}

__global__ void k_prep_small(const float* __restrict__ bih0, const float* __restrict__ bhh0,
                             float* __restrict__ b0s,
                             unsigned short* __restrict__ h2buf,   // [4][Bc][Hc]
                             int* __restrict__ f1, int* __restrict__ f2) {
  int i = blockIdx.x * blockDim.x + threadIdx.x;  // grid covers 4*Bc*Hc = 524288
  if (i < 4096) b0s[i] = bih0[i] + bhh0[i];
  h2buf[i] = 0;
  if (i < 128 * 16) { f1[i] = 0; f2[i] = 0; }
}

// ----------------- layer-0 bulk GEMM (no recurrence; f-gate dead) -----------------
__global__ __launch_bounds__(512, 1) void k_l0(
    const unsigned short* __restrict__ xb, const unsigned short* __restrict__ W0,
    const float* __restrict__ b0s, unsigned short* __restrict__ H0)
{
  const int tid = threadIdx.x;
  const int lane = tid & 63, wid = tid >> 6;
  const int wM = wid >> 2, wN = wid & 3;           // 8 waves: 2(M) x 4(N)
  const int rowbase = blockIdx.x * 32 + wM * 16;
  const int jbase   = blockIdx.y * 64 + wN * 16;
  const int ri = lane & 15, kg = lane >> 4;

  const int r = rowbase + ri;
  const int t = r >> 7, b = r & (Bc - 1);
  const unsigned short* arow = xb + ((size_t)b * Tc + t) * Ec + kg * 8;

  const unsigned short* w0r = W0 + ((size_t)(0 * Hc + jbase + ri)) * Ec + kg * 8;
  const unsigned short* w2r = W0 + ((size_t)(2 * Hc + jbase + ri)) * Ec + kg * 8;
  const unsigned short* w3r = W0 + ((size_t)(3 * Hc + jbase + ri)) * Ec + kg * 8;

  f32x4 ai = {0,0,0,0}, ag = {0,0,0,0}, ao = {0,0,0,0};
#pragma unroll
  for (int kk = 0; kk < Ec / 32; ++kk) {
    bf16x8 a = *(const bf16x8*)(arow + kk * 32);
    ai = MFMA16(a, *(const bf16x8*)(w0r + kk * 32), ai);
    ag = MFMA16(a, *(const bf16x8*)(w2r + kk * 32), ag);
    ao = MFMA16(a, *(const bf16x8*)(w3r + kk * 32), ao);
  }
  const int j = jbase + ri;
  const float bi = b0s[j], bg = b0s[2 * Hc + j], bo = b0s[3 * Hc + j];
#pragma unroll
  for (int q = 0; q < 4; ++q) {
    const int rr = rowbase + kg * 4 + q;
    float c = sigm(ai[q] + bi) * tanhf(ag[q] + bg);
    float h = sigm(ao[q] + bo) * tanhf(c);
    H0[(size_t)rr * Hc + j] = f2bf(h);
  }
}

// ----------------- recurrent kernel: write-once h1 (cached reads) + sc1 h2 -----------------
// 256 WGs x 512 thr (8 waves), 1 WG/CU. WGs 0..127: layer1; 128..255: layer2.
// h1 is FULL-DEPTH [Tc][Bc][Hc] in d_out's upper half: every address written exactly
// once (sc1 write-through, drained pre-signal), so consumers may use PLAIN CACHED
// loads — no L2 line can be stale (launch-boundary acquire + write-once). Each XCD
// then fetches each h1 line once from L3 and serves its ~32 WGs from L2.
// h2 is 4-deep (addresses reused) -> stays on the proven sc1 read path.
// Flags: per-producer slots (64B stride), all relaxed; producer order via the
// compiler's pre-barrier vmcnt(0) drain. No fences, no RMW.
__global__ __launch_bounds__(512, 1) void k_rec(
    const unsigned short* H0,                        // [Tc*Bc][Hc] bf16 (ws)
    const float* __restrict__ Wih, const float* __restrict__ Whh,  // [2][4096][1024] f32
    const float* __restrict__ bih, const float* __restrict__ bhh,  // [2][4096] f32
    unsigned short* h1full,                          // [Tc][Bc][Hc] bf16 (d_out upper half)
    unsigned short* h2buf,                           // [4][Bc][Hc] bf16 (ws)
    int* f1, int* f2,                                // [128] slots x 16 ints (64B stride)
    float* out)                                      // [Tc][Bc][Hc] f32 (d_out)
{
  __shared__ unsigned short Wlds[2 * 64 * 64 * 8];   // 128 KiB: [tile][kstep][lane][8]
  const int tid = threadIdx.x;
  const int lane = tid & 63, wid = tid >> 6;
  const int bid = blockIdx.x;
  const int layer = bid >> 7;
  const int w = bid & 127;
  const int j0 = w * 8;
  const int ri = lane & 15, kg = lane >> 4;

  // ---- prologue: weights fp32 -> bf16 into LDS, fragment-major ----
  const size_t lw = (size_t)layer * 4096 * 1024;
  for (int s = tid; s < 2 * 64 * 64; s += 512) {
    const int l   = s & 63;
    const int kkg = (s >> 6) & 63;
    const int t   = s >> 12;
    const int rr  = l & 15;
    const int gate = t * 2 + (rr >> 3);
    const int R = gate * 1024 + j0 + (rr & 7);
    const int k = kkg * 32 + (l >> 4) * 8;
    const float* src = (k < 1024) ? (Wih + lw + (size_t)R * 1024 + k)
                                  : (Whh + lw + (size_t)R * 1024 + (k - 1024));
    f32x4 v0 = *(const f32x4*)src;
    f32x4 v1 = *(const f32x4*)(src + 4);
    ushort4* d = (ushort4*)(Wlds + (size_t)s * 8);
    d[0] = make_ushort4(f2bf(v0[0]), f2bf(v0[1]), f2bf(v0[2]), f2bf(v0[3]));
    d[1] = make_ushort4(f2bf(v1[0]), f2bf(v1[1]), f2bf(v1[2]), f2bf(v1[3]));
  }

  const int jme = j0 + (ri & 7);
  const int g0 = (ri < 8) ? 0 : 1;                  // tile0: i | f
  const int g1 = (ri < 8) ? 2 : 3;                  // tile1: g | o
  const float bias0 = bih[layer * 4096 + g0 * 1024 + jme] + bhh[layer * 4096 + g0 * 1024 + jme];
  const float bias1 = bih[layer * 4096 + g1 * 1024 + jme] + bhh[layer * 4096 + g1 * 1024 + jme];

  float creg[4] = {0.f, 0.f, 0.f, 0.f};

  const unsigned short* lds0 = Wlds + (size_t)lane * 8;
  const unsigned short* lds1 = Wlds + (size_t)64 * 64 * 8 + (size_t)lane * 8;
  const int arow = wid * 16 + ri;
  const bool lo = (ri < 8);

  __syncthreads();                                  // Wlds ready

  if (layer == 0) {
    // ---------------- layer 1: h1(p) = cell(H0(p), h1(p-1)) ----------------
    for (int p = 0; p < Tc; ++p) {
      // free half: A1 = H0(p), K 0..1023 (cached loads)
      const unsigned short* a1 = H0 + (size_t)p * SLOT + (size_t)arow * Hc + kg * 8;
      f32x4 acc0 = {0,0,0,0}, acc1 = {0,0,0,0};
#pragma unroll
      for (int kk = 0; kk < 32; ++kk) {
        bf16x8 a = *(const bf16x8*)(a1 + kk * 32);
        acc0 = MFMA16(a, *(const bf16x8*)(lds0 + kk * 512), acc0);
        acc1 = MFMA16(a, *(const bf16x8*)(lds1 + kk * 512), acc1);
      }
      // gated half: wait h1(p-1), then PLAIN CACHED loads (write-once slot)
      if (tid < 128 && p >= 1) poll_rlx(f1 + tid * 16, p);
      __syncthreads();
      if (p >= 1) {
        const unsigned short* a2 = h1full + (size_t)(p - 1) * SLOT + (size_t)arow * Hc + kg * 8;
#pragma unroll
        for (int kk = 32; kk < 64; ++kk) {
          bf16x8 a = *(const bf16x8*)(a2 + (kk - 32) * 32);
          acc0 = MFMA16(a, *(const bf16x8*)(lds0 + kk * 512), acc0);
          acc1 = MFMA16(a, *(const bf16x8*)(lds1 + kk * 512), acc1);
        }
      }                                             // p==0: h1(-1)=0 contributes nothing
      // cell epilogue + write-once store to slot p
      unsigned short* hb = h1full + (size_t)p * SLOT;
#pragma unroll
      for (int q = 0; q < 4; ++q) {
        float x0 = acc0[q] + bias0;
        float x1 = acc1[q] + bias1;
        float p0 = __shfl_xor(x0, 8);
        float p1 = __shfl_xor(x1, 8);
        float gi = lo ? x0 : p0;
        float gf = lo ? p0 : x0;
        float gg = lo ? x1 : p1;
        float go = lo ? p1 : x1;
        float cn = sigm(gf) * creg[q] + sigm(gi) * tanhf(gg);
        float hnv = sigm(go) * tanhf(cn);
        creg[q] = cn;
        if (lo) {
          const int rr = wid * 16 + kg * 4 + q;
          stg_c(hb + (size_t)rr * Hc + jme, f2bf(hnv));
        }
      }
      __syncthreads();                              // pre-barrier vmcnt(0): stores ACKed at L3
      if (tid == 0) sig(f1 + w * 16, p + 1);
    }
  } else {
    // ---------------- layer 2: h2(s) = cell(h1(s), h2(s-1)) ----------------
    for (int s = 0; s < Tc; ++s) {
      // own-chain half first: wait h2(s-1); slot (s-1)&3 via sc1 (reused addresses)
      if (tid < 128 && s >= 1) poll_rlx(f2 + tid * 16, s);
      __syncthreads();
      const unsigned short* a2 = h2buf + (size_t)((s - 1) & 3) * SLOT + (size_t)arow * Hc + kg * 8;
      f32x4 acc0 = {0,0,0,0}, acc1 = {0,0,0,0};
#pragma unroll
      for (int kk = 32; kk < 64; ++kk) {
        bf16x8 a = ldg_c(a2 + (kk - 32) * 32);
        acc0 = MFMA16(a, *(const bf16x8*)(lds0 + kk * 512), acc0);
        acc1 = MFMA16(a, *(const bf16x8*)(lds1 + kk * 512), acc1);
      }
      // cross-layer half: wait h1(s), then PLAIN CACHED loads (write-once slot)
      if (tid < 128) poll_rlx(f1 + tid * 16, s + 1);
      __syncthreads();
      const unsigned short* a1 = h1full + (size_t)s * SLOT + (size_t)arow * Hc + kg * 8;
#pragma unroll
      for (int kk = 0; kk < 32; ++kk) {
        bf16x8 a = *(const bf16x8*)(a1 + kk * 32);
        acc0 = MFMA16(a, *(const bf16x8*)(lds0 + kk * 512), acc0);
        acc1 = MFMA16(a, *(const bf16x8*)(lds1 + kk * 512), acc1);
      }
      // cell epilogue + stores
      unsigned short* hb = h2buf + (size_t)(s & 3) * SLOT;
      float* po = out + (size_t)s * SLOT;
#pragma unroll
      for (int q = 0; q < 4; ++q) {
        float x0 = acc0[q] + bias0;
        float x1 = acc1[q] + bias1;
        float p0 = __shfl_xor(x0, 8);
        float p1 = __shfl_xor(x1, 8);
        float gi = lo ? x0 : p0;
        float gf = lo ? p0 : x0;
        float gg = lo ? x1 : p1;
        float go = lo ? p1 : x1;
        float cn = sigm(gf) * creg[q] + sigm(gi) * tanhf(gg);
        float hnv = sigm(go) * tanhf(cn);
        creg[q] = cn;
        if (lo) {
          const int rr = wid * 16 + kg * 4 + q;
          stg_c(hb + (size_t)rr * Hc + jme, f2bf(hnv));
          po[(size_t)rr * Hc + jme] = hnv;          // plain store; never read in-kernel
        }
      }
      __syncthreads();                              // pre-barrier vmcnt(0): stores ACKed at L3
      if (tid == 0) sig(f2 + w * 16, s + 1);
    }
  }
}

// ----------------- launcher -----------------
extern "C" void kernel_launch(void* const* d_in, const int* in_sizes, int n_in,
                              void* d_out, int out_size, void* d_ws, size_t ws_size,
                              hipStream_t stream) {
  const float* x     = (const float*)d_in[0];
  const float* W_ih0 = (const float*)d_in[1];
  // d_in[2] = W_hh0 (unused: layer-0 state is always zero)
  const float* b_ih0 = (const float*)d_in[3];
  const float* b_hh0 = (const float*)d_in[4];
  const float* W_ihr = (const float*)d_in[5];
  const float* W_hhr = (const float*)d_in[6];
  const float* b_ihr = (const float*)d_in[7];
  const float* b_hhr = (const float*)d_in[8];

  // ws layout (~65 MB): H0 64MB + h2buf 1MB + flags
  char* ws = (char*)d_ws;
  constexpr size_t H0_OFF  = 0;                                   // Tc*Bc*Hc bf16 = 64 MB
  constexpr size_t H2B_OFF = H0_OFF + (size_t)Tc * Bc * Hc * 2;   // 4*Bc*Hc bf16 = 1 MB
  constexpr size_t F1_OFF  = H2B_OFF + (size_t)4 * Bc * Hc * 2;   // 8 KB
  constexpr size_t F2_OFF  = F1_OFF + 128 * 16 * 4;               // 8 KB

  unsigned short* H0    = (unsigned short*)(ws + H0_OFF);
  unsigned short* h2buf = (unsigned short*)(ws + H2B_OFF);
  float* b0s = (float*)(ws + F2_OFF + 128 * 16 * 4);              // 16 KB, after flags
  int* f1 = (int*)(ws + F1_OFF);
  int* f2 = (int*)(ws + F2_OFF);

  // d_out layout during compute:
  //   lower half transient: xb (bf16 x, 32MB @0) + W0b (bf16 W_ih0, 4MB @32MB) — read
  //     only by k_l0, which completes before k_rec starts (stream order); later fully
  //     overwritten by out[s] stores.
  //   upper half: h1full [Tc][Bc][Hc] bf16 (write-once slots). out[s] (s>=128) overwrites
  //     h1 slots q in {2s-256, 2s-255}; writer waited d1[s]>=128 and d2[s-1]>=128, which
  //     orders it after ALL reads of those slots (layer-1 phase q+1 <= s, layer-2 step
  //     q <= s-1) and after their producer writes. Re-derived incl. s=255 and WG lag.
  unsigned short* xb     = (unsigned short*)d_out;
  unsigned short* W0b    = (unsigned short*)d_out + (size_t)Bc * Tc * Ec;
  unsigned short* h1full = (unsigned short*)d_out + (size_t)Tc * Bc * Hc;
  float* out = (float*)d_out;

  int n0 = 4096 * 512;
  k_cvt_bf16<<<n0 / 1024, 256, 0, stream>>>(W_ih0, W0b, n0);
  int nx = Bc * Tc * Ec;
  k_cvt_bf16<<<nx / 1024, 256, 0, stream>>>(x, xb, nx);
  k_prep_small<<<2048, 256, 0, stream>>>(b_ih0, b_hh0, b0s, h2buf, f1, f2);
  k_l0<<<dim3(1024, 16), 512, 0, stream>>>(xb, W0b, b0s, H0);

  const float* Wih = W_ihr; const float* Whh = W_hhr;
  const float* bih = b_ihr; const float* bhh = b_hhr;
  void* kargs[] = { &H0, &Wih, &Whh, &bih, &bhh, &h1full, &h2buf, &f1, &f2, &out };
  hipLaunchCooperativeKernel((void*)k_rec, dim3(256), dim3(512), kargs, 0, stream);
}

// Round 9
// 6856.528 us; speedup vs baseline: 1.4647x; 1.0238x over previous
//
#include <hip/hip_runtime.h>
#include <hip/hip_cooperative_groups.h>

static constexpr int Bc = 128;   // batch
static constexpr int Tc = 256;   // timesteps
static constexpr int Ec = 512;   // input embed
static constexpr int Hc = 1024;  // hidden
static constexpr int SLOT = Bc * Hc;  // one h-state tile (elems)

using bf16x8 = __attribute__((ext_vector_type(8))) short;
using f32x4  = __attribute__((ext_vector_type(4))) float;

__device__ __forceinline__ unsigned short f2bf(float f) {
  unsigned int u = __float_as_uint(f);
  u += 0x7FFFu + ((u >> 16) & 1u);
  return (unsigned short)(u >> 16);
}
__device__ __forceinline__ float sigm(float x) { return 1.0f / (1.0f + __expf(-x)); }

#define MFMA16(A, Bf, C) __builtin_amdgcn_mfma_f32_16x16x32_bf16((A), (Bf), (C), 0, 0, 0)

// ---- fence-free primitives on the signal path (no wbl2 anywhere) ----
__device__ __forceinline__ void poll_rlx(const int* p, int tgt) {
  while (__hip_atomic_load(p, __ATOMIC_RELAXED, __HIP_MEMORY_SCOPE_AGENT) < tgt)
    __builtin_amdgcn_s_sleep(1);
}
__device__ __forceinline__ void sig(int* p, int v) {
  __hip_atomic_store(p, v, __ATOMIC_RELAXED, __HIP_MEMORY_SCOPE_AGENT);
}
// L3 write-through 2B store: produced value lands at the coherence point pre-signal
__device__ __forceinline__ void stg_c(unsigned short* p, unsigned short v) {
  __hip_atomic_store(p, v, __ATOMIC_RELAXED, __HIP_MEMORY_SCOPE_AGENT);
}

// ----------------- prep kernels -----------------
__global__ void k_cvt_bf16(const float* __restrict__ src, unsigned short* __restrict__ dst, int n) {
  int i = (blockIdx.x * blockDim.x + threadIdx.x) * 4;
  if (i + 3 < n) {
    f32x4 v = *(const f32x4*)(src + i);
    *(ushort4*)(dst + i) = make_ushort4(f2bf(v[0]), f2bf(v[1]), f2bf(v[2]), f2bf(v[3]));
  }
}

__global__ void k_prep_small(const float* __restrict__ bih0, const float* __restrict__ bhh0,
                             float* __restrict__ b0s,
                             unsigned short* __restrict__ h2buf,   // [4][Bc][Hc]
                             int* __restrict__ f1, int* __restrict__ f2) {
  int i = blockIdx.x * blockDim.x + threadIdx.x;  // grid covers 4*Bc*Hc = 524288
  if (i < 4096) b0s[i] = bih0[i] + bhh0[i];
  h2buf[i] = 0;
  if (i < 128 * 16) { f1[i] = 0; f2[i] = 0; }
}

// ----------------- layer-0 bulk GEMM (no recurrence; f-gate dead) -----------------
__global__ __launch_bounds__(512, 1) void k_l0(
    const unsigned short* __restrict__ xb, const unsigned short* __restrict__ W0,
    const float* __restrict__ b0s, unsigned short* __restrict__ H0)
{
  const int tid = threadIdx.x;
  const int lane = tid & 63, wid = tid >> 6;
  const int wM = wid >> 2, wN = wid & 3;           // 8 waves: 2(M) x 4(N)
  const int rowbase = blockIdx.x * 32 + wM * 16;
  const int jbase   = blockIdx.y * 64 + wN * 16;
  const int ri = lane & 15, kg = lane >> 4;

  const int r = rowbase + ri;
  const int t = r >> 7, b = r & (Bc - 1);
  const unsigned short* arow = xb + ((size_t)b * Tc + t) * Ec + kg * 8;

  const unsigned short* w0r = W0 + ((size_t)(0 * Hc + jbase + ri)) * Ec + kg * 8;
  const unsigned short* w2r = W0 + ((size_t)(2 * Hc + jbase + ri)) * Ec + kg * 8;
  const unsigned short* w3r = W0 + ((size_t)(3 * Hc + jbase + ri)) * Ec + kg * 8;

  f32x4 ai = {0,0,0,0}, ag = {0,0,0,0}, ao = {0,0,0,0};
#pragma unroll
  for (int kk = 0; kk < Ec / 32; ++kk) {
    bf16x8 a = *(const bf16x8*)(arow + kk * 32);
    ai = MFMA16(a, *(const bf16x8*)(w0r + kk * 32), ai);
    ag = MFMA16(a, *(const bf16x8*)(w2r + kk * 32), ag);
    ao = MFMA16(a, *(const bf16x8*)(w3r + kk * 32), ao);
  }
  const int j = jbase + ri;
  const float bi = b0s[j], bg = b0s[2 * Hc + j], bo = b0s[3 * Hc + j];
#pragma unroll
  for (int q = 0; q < 4; ++q) {
    const int rr = rowbase + kg * 4 + q;
    float c = sigm(ai[q] + bi) * tanhf(ag[q] + bg);
    float h = sigm(ao[q] + bo) * tanhf(c);
    H0[(size_t)rr * Hc + j] = f2bf(h);
  }
}

// ----------------- recurrent kernel: all-cached reads; single inv per L2-step ------------
// 256 WGs x 512 thr (8 waves), 1 WG/CU. WGs 0..127: layer1; 128..255: layer2.
// h1 full-depth write-once in d_out upper half (plain cached reads, no fence needed —
// replay-stale lines hold identical values by determinism). h2 4-deep ring: sc1
// write-through stores + PLAIN cached reads guarded by ONE acquire fence (buffer_inv)
// per step (ring addresses are the only reused-and-rewritten data; our access pattern
// has no cross-phase L2 reuse, so the inv costs ~nothing in locality).
// Layer-2 chain shortened: cross-half (h1) first (f1 always ahead), out stores after
// the f2 signal (drain in next step's barrier).
__global__ __launch_bounds__(512, 1) void k_rec(
    const unsigned short* H0,                        // [Tc*Bc][Hc] bf16 (ws)
    const float* __restrict__ Wih, const float* __restrict__ Whh,  // [2][4096][1024] f32
    const float* __restrict__ bih, const float* __restrict__ bhh,  // [2][4096] f32
    unsigned short* h1full,                          // [Tc][Bc][Hc] bf16 (d_out upper half)
    unsigned short* h2buf,                           // [4][Bc][Hc] bf16 (ws)
    int* f1, int* f2,                                // [128] slots x 16 ints (64B stride)
    float* out)                                      // [Tc][Bc][Hc] f32 (d_out)
{
  __shared__ unsigned short Wlds[2 * 64 * 64 * 8];   // 128 KiB: [tile][kstep][lane][8]
  const int tid = threadIdx.x;
  const int lane = tid & 63, wid = tid >> 6;
  const int bid = blockIdx.x;
  const int layer = bid >> 7;
  const int w = bid & 127;
  const int j0 = w * 8;
  const int ri = lane & 15, kg = lane >> 4;

  // ---- prologue: weights fp32 -> bf16 into LDS, fragment-major ----
  const size_t lw = (size_t)layer * 4096 * 1024;
  for (int s = tid; s < 2 * 64 * 64; s += 512) {
    const int l   = s & 63;
    const int kkg = (s >> 6) & 63;
    const int t   = s >> 12;
    const int rr  = l & 15;
    const int gate = t * 2 + (rr >> 3);
    const int R = gate * 1024 + j0 + (rr & 7);
    const int k = kkg * 32 + (l >> 4) * 8;
    const float* src = (k < 1024) ? (Wih + lw + (size_t)R * 1024 + k)
                                  : (Whh + lw + (size_t)R * 1024 + (k - 1024));
    f32x4 v0 = *(const f32x4*)src;
    f32x4 v1 = *(const f32x4*)(src + 4);
    ushort4* d = (ushort4*)(Wlds + (size_t)s * 8);
    d[0] = make_ushort4(f2bf(v0[0]), f2bf(v0[1]), f2bf(v0[2]), f2bf(v0[3]));
    d[1] = make_ushort4(f2bf(v1[0]), f2bf(v1[1]), f2bf(v1[2]), f2bf(v1[3]));
  }

  const int jme = j0 + (ri & 7);
  const int g0 = (ri < 8) ? 0 : 1;                  // tile0: i | f
  const int g1 = (ri < 8) ? 2 : 3;                  // tile1: g | o
  const float bias0 = bih[layer * 4096 + g0 * 1024 + jme] + bhh[layer * 4096 + g0 * 1024 + jme];
  const float bias1 = bih[layer * 4096 + g1 * 1024 + jme] + bhh[layer * 4096 + g1 * 1024 + jme];

  float creg[4] = {0.f, 0.f, 0.f, 0.f};

  const unsigned short* lds0 = Wlds + (size_t)lane * 8;
  const unsigned short* lds1 = Wlds + (size_t)64 * 64 * 8 + (size_t)lane * 8;
  const int arow = wid * 16 + ri;
  const bool lo = (ri < 8);

  __syncthreads();                                  // Wlds ready

  if (layer == 0) {
    // ---------------- layer 1: h1(p) = cell(H0(p), h1(p-1)) ----------------
    for (int p = 0; p < Tc; ++p) {
      // free half: A1 = H0(p), K 0..1023 (cached loads)
      const unsigned short* a1 = H0 + (size_t)p * SLOT + (size_t)arow * Hc + kg * 8;
      f32x4 acc0 = {0,0,0,0}, acc1 = {0,0,0,0};
#pragma unroll
      for (int kk = 0; kk < 32; ++kk) {
        bf16x8 a = *(const bf16x8*)(a1 + kk * 32);
        acc0 = MFMA16(a, *(const bf16x8*)(lds0 + kk * 512), acc0);
        acc1 = MFMA16(a, *(const bf16x8*)(lds1 + kk * 512), acc1);
      }
      // gated half: wait h1(p-1), then PLAIN CACHED loads (write-once slot)
      if (tid < 128 && p >= 1) poll_rlx(f1 + tid * 16, p);
      __syncthreads();
      if (p >= 1) {
        const unsigned short* a2 = h1full + (size_t)(p - 1) * SLOT + (size_t)arow * Hc + kg * 8;
#pragma unroll
        for (int kk = 32; kk < 64; ++kk) {
          bf16x8 a = *(const bf16x8*)(a2 + (kk - 32) * 32);
          acc0 = MFMA16(a, *(const bf16x8*)(lds0 + kk * 512), acc0);
          acc1 = MFMA16(a, *(const bf16x8*)(lds1 + kk * 512), acc1);
        }
      }                                             // p==0: h1(-1)=0 contributes nothing
      // cell epilogue + write-once store to slot p
      unsigned short* hb = h1full + (size_t)p * SLOT;
#pragma unroll
      for (int q = 0; q < 4; ++q) {
        float x0 = acc0[q] + bias0;
        float x1 = acc1[q] + bias1;
        float p0 = __shfl_xor(x0, 8);
        float p1 = __shfl_xor(x1, 8);
        float gi = lo ? x0 : p0;
        float gf = lo ? p0 : x0;
        float gg = lo ? x1 : p1;
        float go = lo ? p1 : x1;
        float cn = sigm(gf) * creg[q] + sigm(gi) * tanhf(gg);
        float hnv = sigm(go) * tanhf(cn);
        creg[q] = cn;
        if (lo) {
          const int rr = wid * 16 + kg * 4 + q;
          stg_c(hb + (size_t)rr * Hc + jme, f2bf(hnv));
        }
      }
      __syncthreads();                              // pre-barrier vmcnt(0): stores ACKed at L3
      if (tid == 0) sig(f1 + w * 16, p + 1);
    }
  } else {
    // ---------------- layer 2: h2(s) = cell(h1(s), h2(s-1)) ----------------
    for (int s = 0; s < Tc; ++s) {
      // cross-layer half FIRST (f1 is nearly always already satisfied — layer-1 is
      // self-chained only and runs ahead). Plain cached loads of write-once h1 slot s.
      if (tid < 128) poll_rlx(f1 + tid * 16, s + 1);
      __syncthreads();
      const unsigned short* a1 = h1full + (size_t)s * SLOT + (size_t)arow * Hc + kg * 8;
      f32x4 acc0 = {0,0,0,0}, acc1 = {0,0,0,0};
#pragma unroll
      for (int kk = 0; kk < 32; ++kk) {
        bf16x8 a = *(const bf16x8*)(a1 + kk * 32);
        acc0 = MFMA16(a, *(const bf16x8*)(lds0 + kk * 512), acc0);
        acc1 = MFMA16(a, *(const bf16x8*)(lds1 + kk * 512), acc1);
      }
      // own-chain half: wait h2(s-1), ONE acquire fence (buffer_inv) per step, then
      // PLAIN cached loads of the ring slot. Fence is unconditional: at s==0 it also
      // flushes replay-stale h2 zero-lines from the previous graph replay.
      if (tid < 128 && s >= 1) poll_rlx(f2 + tid * 16, s);
      __syncthreads();
      __builtin_amdgcn_fence(__ATOMIC_ACQUIRE, "agent");
      const unsigned short* a2 = h2buf + (size_t)((s - 1) & 3) * SLOT + (size_t)arow * Hc + kg * 8;
#pragma unroll
      for (int kk = 32; kk < 64; ++kk) {
        bf16x8 a = *(const bf16x8*)(a2 + (kk - 32) * 32);
        acc0 = MFMA16(a, *(const bf16x8*)(lds0 + kk * 512), acc0);
        acc1 = MFMA16(a, *(const bf16x8*)(lds1 + kk * 512), acc1);
      }
      // cell epilogue; h2 stores now, out stores AFTER the signal
      unsigned short* hb = h2buf + (size_t)(s & 3) * SLOT;
      float hnr[4];
#pragma unroll
      for (int q = 0; q < 4; ++q) {
        float x0 = acc0[q] + bias0;
        float x1 = acc1[q] + bias1;
        float p0 = __shfl_xor(x0, 8);
        float p1 = __shfl_xor(x1, 8);
        float gi = lo ? x0 : p0;
        float gf = lo ? p0 : x0;
        float gg = lo ? x1 : p1;
        float go = lo ? p1 : x1;
        float cn = sigm(gf) * creg[q] + sigm(gi) * tanhf(gg);
        float hnv = sigm(go) * tanhf(cn);
        creg[q] = cn;
        hnr[q] = hnv;
        if (lo) {
          const int rr = wid * 16 + kg * 4 + q;
          stg_c(hb + (size_t)rr * Hc + jme, f2bf(hnv));
        }
      }
      __syncthreads();                              // drains h2 stg_c (+ prev out stores)
      if (tid == 0) sig(f2 + w * 16, s + 1);
      // out[s] off the signal chain; aliasing with h1 slots {2s-256,2s-255} is ordered
      // by the f1/f2 waits above (issued later than r8 = strictly safer).
      if (lo) {
        float* po = out + (size_t)s * SLOT;
#pragma unroll
        for (int q = 0; q < 4; ++q) {
          const int rr = wid * 16 + kg * 4 + q;
          po[(size_t)rr * Hc + jme] = hnr[q];
        }
      }
    }
  }
}

// ----------------- launcher -----------------
extern "C" void kernel_launch(void* const* d_in, const int* in_sizes, int n_in,
                              void* d_out, int out_size, void* d_ws, size_t ws_size,
                              hipStream_t stream) {
  const float* x     = (const float*)d_in[0];
  const float* W_ih0 = (const float*)d_in[1];
  // d_in[2] = W_hh0 (unused: layer-0 state is always zero)
  const float* b_ih0 = (const float*)d_in[3];
  const float* b_hh0 = (const float*)d_in[4];
  const float* W_ihr = (const float*)d_in[5];
  const float* W_hhr = (const float*)d_in[6];
  const float* b_ihr = (const float*)d_in[7];
  const float* b_hhr = (const float*)d_in[8];

  // ws layout (~65 MB): H0 64MB + h2buf 1MB + flags
  char* ws = (char*)d_ws;
  constexpr size_t H0_OFF  = 0;                                   // Tc*Bc*Hc bf16 = 64 MB
  constexpr size_t H2B_OFF = H0_OFF + (size_t)Tc * Bc * Hc * 2;   // 4*Bc*Hc bf16 = 1 MB
  constexpr size_t F1_OFF  = H2B_OFF + (size_t)4 * Bc * Hc * 2;   // 8 KB
  constexpr size_t F2_OFF  = F1_OFF + 128 * 16 * 4;               // 8 KB

  unsigned short* H0    = (unsigned short*)(ws + H0_OFF);
  unsigned short* h2buf = (unsigned short*)(ws + H2B_OFF);
  float* b0s = (float*)(ws + F2_OFF + 128 * 16 * 4);              // 16 KB, after flags
  int* f1 = (int*)(ws + F1_OFF);
  int* f2 = (int*)(ws + F2_OFF);

  // d_out layout during compute (unchanged from round 8; alias proof carries over):
  //   lower half transient: xb (32MB @0) + W0b (4MB @32MB), read only by k_l0.
  //   upper half: h1full [Tc][Bc][Hc] bf16 write-once slots; out[s] (s>=128) overwrites
  //   h1 slots {2s-256, 2s-255} only after f1>=s+1 and f2>=s order it past all readers.
  unsigned short* xb     = (unsigned short*)d_out;
  unsigned short* W0b    = (unsigned short*)d_out + (size_t)Bc * Tc * Ec;
  unsigned short* h1full = (unsigned short*)d_out + (size_t)Tc * Bc * Hc;
  float* out = (float*)d_out;

  int n0 = 4096 * 512;
  k_cvt_bf16<<<n0 / 1024, 256, 0, stream>>>(W_ih0, W0b, n0);
  int nx = Bc * Tc * Ec;
  k_cvt_bf16<<<nx / 1024, 256, 0, stream>>>(x, xb, nx);
  k_prep_small<<<2048, 256, 0, stream>>>(b_ih0, b_hh0, b0s, h2buf, f1, f2);
  k_l0<<<dim3(1024, 16), 512, 0, stream>>>(xb, W0b, b0s, H0);

  const float* Wih = W_ihr; const float* Whh = W_hhr;
  const float* bih = b_ihr; const float* bhh = b_hhr;
  void* kargs[] = { &H0, &Wih, &Whh, &bih, &bhh, &h1full, &h2buf, &f1, &f2, &out };
  hipLaunchCooperativeKernel((void*)k_rec, dim3(256), dim3(512), kargs, 0, stream);
}

// Round 11
// 6200.493 us; speedup vs baseline: 1.6197x; 1.1058x over previous
//
#include <hip/hip_runtime.h>

static constexpr int Bc = 128;   // batch
static constexpr int Tc = 256;   // timesteps
static constexpr int Ec = 512;   // input embed
static constexpr int Hc = 1024;  // hidden
static constexpr int SLOT = Bc * Hc;  // one h-state tile (elems)
// chunked h-state layout: [slot][chunk(128)][row(128)][col(8)] bf16
// elem addr (ushorts, within slot) = chunk*1024 + row*8 + col ; chunk = globalcol>>3

using bf16x8 = __attribute__((ext_vector_type(8))) short;
using f32x4  = __attribute__((ext_vector_type(4))) float;

__device__ __forceinline__ unsigned short f2bf(float f) {
  unsigned int u = __float_as_uint(f);
  u += 0x7FFFu + ((u >> 16) & 1u);
  return (unsigned short)(u >> 16);
}
__device__ __forceinline__ float sigm(float x) { return 1.0f / (1.0f + __expf(-x)); }

#define MFMA16(A, Bf, C) __builtin_amdgcn_mfma_f32_16x16x32_bf16((A), (Bf), (C), 0, 0, 0)

// ---- sync primitives: UNCHANGED from round 9 (proven) ----
__device__ __forceinline__ void poll_rlx(const int* p, int tgt) {
  while (__hip_atomic_load(p, __ATOMIC_RELAXED, __HIP_MEMORY_SCOPE_AGENT) < tgt)
    __builtin_amdgcn_s_sleep(1);
}
__device__ __forceinline__ void sig(int* p, int v) {
  __hip_atomic_store(p, v, __ATOMIC_RELAXED, __HIP_MEMORY_SCOPE_AGENT);
}
__device__ __forceinline__ void stg_c(unsigned short* p, unsigned short v) {
  __hip_atomic_store(p, v, __ATOMIC_RELAXED, __HIP_MEMORY_SCOPE_AGENT);
}

// ----------------- prep kernels -----------------
__global__ void k_cvt_bf16(const float* __restrict__ src, unsigned short* __restrict__ dst, int n) {
  int i = (blockIdx.x * blockDim.x + threadIdx.x) * 4;
  if (i + 3 < n) {
    f32x4 v = *(const f32x4*)(src + i);
    *(ushort4*)(dst + i) = make_ushort4(f2bf(v[0]), f2bf(v[1]), f2bf(v[2]), f2bf(v[3]));
  }
}

__global__ void k_prep_small(const float* __restrict__ bih0, const float* __restrict__ bhh0,
                             float* __restrict__ b0s,
                             unsigned short* __restrict__ h2c,     // [4][SLOT]
                             int* __restrict__ f1, int* __restrict__ f2) {
  int i = blockIdx.x * blockDim.x + threadIdx.x;  // grid covers 4*SLOT = 524288
  if (i < 4096) b0s[i] = bih0[i] + bhh0[i];
  h2c[i] = 0;
  if (i < 128 * 16) { f1[i] = 0; f2[i] = 0; }
}

// ----------------- layer-0 bulk GEMM (no recurrence; f-gate dead) -----------------
// writes H0 in CHUNKED layout
__global__ __launch_bounds__(512, 1) void k_l0(
    const unsigned short* __restrict__ xb, const unsigned short* __restrict__ W0,
    const float* __restrict__ b0s, unsigned short* __restrict__ H0)
{
  const int tid = threadIdx.x;
  const int lane = tid & 63, wid = tid >> 6;
  const int wM = wid >> 2, wN = wid & 3;           // 8 waves: 2(M) x 4(N)
  const int rowbase = blockIdx.x * 32 + wM * 16;
  const int jbase   = blockIdx.y * 64 + wN * 16;
  const int ri = lane & 15, kg = lane >> 4;

  const int r = rowbase + ri;
  const int t = r >> 7, b = r & (Bc - 1);
  const unsigned short* arow = xb + ((size_t)b * Tc + t) * Ec + kg * 8;

  const unsigned short* w0r = W0 + ((size_t)(0 * Hc + jbase + ri)) * Ec + kg * 8;
  const unsigned short* w2r = W0 + ((size_t)(2 * Hc + jbase + ri)) * Ec + kg * 8;
  const unsigned short* w3r = W0 + ((size_t)(3 * Hc + jbase + ri)) * Ec + kg * 8;

  f32x4 ai = {0,0,0,0}, ag = {0,0,0,0}, ao = {0,0,0,0};
#pragma unroll
  for (int kk = 0; kk < Ec / 32; ++kk) {
    bf16x8 a = *(const bf16x8*)(arow + kk * 32);
    ai = MFMA16(a, *(const bf16x8*)(w0r + kk * 32), ai);
    ag = MFMA16(a, *(const bf16x8*)(w2r + kk * 32), ag);
    ao = MFMA16(a, *(const bf16x8*)(w3r + kk * 32), ao);
  }
  const int j = jbase + ri;
  const float bi = b0s[j], bg = b0s[2 * Hc + j], bo = b0s[3 * Hc + j];
#pragma unroll
  for (int q = 0; q < 4; ++q) {
    const int rr = rowbase + kg * 4 + q;
    float c = sigm(ai[q] + bi) * tanhf(ag[q] + bg);
    float h = sigm(ao[q] + bo) * tanhf(c);
    // chunked store: slot = rr>>7, row = rr&127, chunk = j>>3, col = j&7
    H0[(size_t)(rr >> 7) * SLOT + (size_t)(j >> 3) * 1024 + (size_t)(rr & 127) * 8 + (j & 7)] = f2bf(h);
  }
}

// ----------------- recurrent kernel: 4-wave/2-subtile + chunked layouts + r9 sync ----------
// 256 WGs x 256 thr (4 waves), 1 WG/CU (LDS 128KB caps occupancy at 1/CU, so a PLAIN
// launch of grid=256 co-schedules all WGs — cooperative launch not needed since no
// grid.sync; hipLaunchCooperativeKernel silently failed at blockDim=256 in r4/r10).
// WGs 0..127: layer1; 128..255: layer2. Each wave owns 32 batch rows as 2 M-subtiles
// sharing every B-fragment read (ds_read traffic halved vs 8-wave). h-state tensors
// CHUNKED so each WG's stores are a dense 2KB block (no write amplification).
// Sync protocol identical to round 9 (proven).
__global__ __launch_bounds__(256, 1) void k_rec(
    const unsigned short* H0,                        // [256][SLOT] chunked (ws)
    const float* __restrict__ Wih, const float* __restrict__ Whh,  // [2][4096][1024] f32
    const float* __restrict__ bih, const float* __restrict__ bhh,  // [2][4096] f32
    unsigned short* h1c,                             // [Tc][SLOT] chunked (d_out upper half)
    unsigned short* h2c,                             // [4][SLOT] chunked (ws)
    int* f1, int* f2,                                // [128] slots x 16 ints (64B stride)
    float* out)                                      // [Tc][Bc][Hc] f32 (d_out)
{
  __shared__ unsigned short Wlds[2 * 64 * 64 * 8];   // 128 KiB: [tile][kstep][lane][8]
  const int tid = threadIdx.x;
  const int lane = tid & 63, wid = tid >> 6;         // 4 waves
  const int bid = blockIdx.x;
  const int layer = bid >> 7;
  const int w = bid & 127;
  const int j0 = w * 8;
  const int ri = lane & 15, kg = lane >> 4;

  // ---- prologue: weights fp32 -> bf16 into LDS, fragment-major (unchanged math) ----
  const size_t lw = (size_t)layer * 4096 * 1024;
  for (int s = tid; s < 2 * 64 * 64; s += 256) {
    const int l   = s & 63;
    const int kkg = (s >> 6) & 63;
    const int t   = s >> 12;
    const int rr  = l & 15;
    const int gate = t * 2 + (rr >> 3);
    const int R = gate * 1024 + j0 + (rr & 7);
    const int k = kkg * 32 + (l >> 4) * 8;
    const float* src = (k < 1024) ? (Wih + lw + (size_t)R * 1024 + k)
                                  : (Whh + lw + (size_t)R * 1024 + (k - 1024));
    f32x4 v0 = *(const f32x4*)src;
    f32x4 v1 = *(const f32x4*)(src + 4);
    ushort4* d = (ushort4*)(Wlds + (size_t)s * 8);
    d[0] = make_ushort4(f2bf(v0[0]), f2bf(v0[1]), f2bf(v0[2]), f2bf(v0[3]));
    d[1] = make_ushort4(f2bf(v1[0]), f2bf(v1[1]), f2bf(v1[2]), f2bf(v1[3]));
  }

  const int jme = j0 + (ri & 7);
  const int g0 = (ri < 8) ? 0 : 1;                  // tile0: i | f
  const int g1 = (ri < 8) ? 2 : 3;                  // tile1: g | o
  const float bias0 = bih[layer * 4096 + g0 * 1024 + jme] + bhh[layer * 4096 + g0 * 1024 + jme];
  const float bias1 = bih[layer * 4096 + g1 * 1024 + jme] + bhh[layer * 4096 + g1 * 1024 + jme];

  float c0[4]  = {0.f, 0.f, 0.f, 0.f};              // c-state rows wid*32 + kg*4+q
  float c1s[4] = {0.f, 0.f, 0.f, 0.f};              // c-state rows +16

  const unsigned short* lds0 = Wlds + (size_t)lane * 8;
  const unsigned short* lds1 = Wlds + (size_t)64 * 64 * 8 + (size_t)lane * 8;
  // chunked A-fragment per-lane base: chunk = kk*4+kg, row = wid*32+ri (+16 hi)
  // ushort offset = kk*4096 + kg*1024 + row*8
  const int abase = kg * 1024 + (wid * 32 + ri) * 8;
  const bool lo = (ri < 8);

  __syncthreads();                                  // Wlds ready

#define HALF_MM4(Abase, LDSOFF)                                             \
  {                                                                         \
    const unsigned short* ap_ = (Abase) + abase;                            \
    _Pragma("unroll")                                                       \
    for (int kk = 0; kk < 32; ++kk) {                                       \
      bf16x8 b0 = *(const bf16x8*)(lds0 + (LDSOFF) + kk * 512);             \
      bf16x8 b1 = *(const bf16x8*)(lds1 + (LDSOFF) + kk * 512);             \
      bf16x8 vlo = *(const bf16x8*)(ap_ + kk * 4096);                       \
      bf16x8 vhi = *(const bf16x8*)(ap_ + kk * 4096 + 128);                 \
      acc00 = MFMA16(vlo, b0, acc00);                                       \
      acc01 = MFMA16(vlo, b1, acc01);                                       \
      acc10 = MFMA16(vhi, b0, acc10);                                       \
      acc11 = MFMA16(vhi, b1, acc11);                                       \
    }                                                                       \
  }

#define CELL4(accA, accB, cre, hnarr)                                       \
  _Pragma("unroll")                                                         \
  for (int q = 0; q < 4; ++q) {                                             \
    float x0 = accA[q] + bias0;                                             \
    float x1 = accB[q] + bias1;                                             \
    float p0 = __shfl_xor(x0, 8);                                           \
    float p1 = __shfl_xor(x1, 8);                                           \
    float gi = lo ? x0 : p0;                                                \
    float gf = lo ? p0 : x0;                                                \
    float gg = lo ? x1 : p1;                                                \
    float go = lo ? p1 : x1;                                                \
    float cn = sigm(gf) * cre[q] + sigm(gi) * tanhf(gg);                    \
    hnarr[q] = sigm(go) * tanhf(cn);                                        \
    cre[q] = cn;                                                            \
  }

  if (layer == 0) {
    // ---------------- layer 1: h1(p) = cell(H0(p), h1(p-1)) ----------------
    for (int p = 0; p < Tc; ++p) {
      f32x4 acc00 = {0,0,0,0}, acc01 = {0,0,0,0}, acc10 = {0,0,0,0}, acc11 = {0,0,0,0};
      // free half: A = H0 slot p (chunked, cached)
      HALF_MM4(H0 + (size_t)p * SLOT, 0)
      // gated half: wait h1(p-1), then plain cached loads (write-once slot)
      if (tid < 128 && p >= 1) poll_rlx(f1 + tid * 16, p);
      __syncthreads();
      if (p >= 1) {
        HALF_MM4(h1c + (size_t)(p - 1) * SLOT, 32 * 512)
      }
      // cell epilogue + dense chunked write-once stores to slot p
      float hn0[4], hn1[4];
      CELL4(acc00, acc01, c0, hn0)
      CELL4(acc10, acc11, c1s, hn1)
      if (lo) {
        unsigned short* hb = h1c + (size_t)p * SLOT + (size_t)w * 1024 + (ri & 7);
#pragma unroll
        for (int q = 0; q < 4; ++q) {
          const int r0 = wid * 32 + kg * 4 + q;
          stg_c(hb + (size_t)r0 * 8, f2bf(hn0[q]));
          stg_c(hb + (size_t)(r0 + 16) * 8, f2bf(hn1[q]));
        }
      }
      __syncthreads();                              // pre-barrier vmcnt(0): stores ACKed at L3
      if (tid == 0) sig(f1 + w * 16, p + 1);
    }
  } else {
    // ---------------- layer 2: h2(s) = cell(h1(s), h2(s-1)) ----------------
    for (int s = 0; s < Tc; ++s) {
      // cross-layer half first (f1 nearly always satisfied; layer-1 runs ahead)
      if (tid < 128) poll_rlx(f1 + tid * 16, s + 1);
      __syncthreads();
      f32x4 acc00 = {0,0,0,0}, acc01 = {0,0,0,0}, acc10 = {0,0,0,0}, acc11 = {0,0,0,0};
      HALF_MM4(h1c + (size_t)s * SLOT, 0)
      // own-chain half: wait h2(s-1); one acquire fence (buffer_inv) per step; cached
      // ring reads. Fence unconditional (flushes replay-stale ring lines at s==0 too).
      if (tid < 128 && s >= 1) poll_rlx(f2 + tid * 16, s);
      __syncthreads();
      __builtin_amdgcn_fence(__ATOMIC_ACQUIRE, "agent");
      HALF_MM4(h2c + (size_t)((s - 1) & 3) * SLOT, 32 * 512)
      // cell epilogue; h2 chunked stg_c stores now, out stores AFTER the signal
      float hn0[4], hn1[4];
      CELL4(acc00, acc01, c0, hn0)
      CELL4(acc10, acc11, c1s, hn1)
      if (lo) {
        unsigned short* hb = h2c + (size_t)(s & 3) * SLOT + (size_t)w * 1024 + (ri & 7);
#pragma unroll
        for (int q = 0; q < 4; ++q) {
          const int r0 = wid * 32 + kg * 4 + q;
          stg_c(hb + (size_t)r0 * 8, f2bf(hn0[q]));
          stg_c(hb + (size_t)(r0 + 16) * 8, f2bf(hn1[q]));
        }
      }
      __syncthreads();                              // drains h2 stg_c (+ prev out stores)
      if (tid == 0) sig(f2 + w * 16, s + 1);
      // out[s] (fixed row-major layout) off the signal chain; h1-alias ordering is
      // inherited from the f1/f2 waits above (same proof as rounds 8/9).
      if (lo) {
        float* po = out + (size_t)s * SLOT;
#pragma unroll
        for (int q = 0; q < 4; ++q) {
          const int r0 = wid * 32 + kg * 4 + q;
          po[(size_t)r0 * Hc + jme] = hn0[q];
          po[(size_t)(r0 + 16) * Hc + jme] = hn1[q];
        }
      }
    }
  }
}

// ----------------- launcher -----------------
extern "C" void kernel_launch(void* const* d_in, const int* in_sizes, int n_in,
                              void* d_out, int out_size, void* d_ws, size_t ws_size,
                              hipStream_t stream) {
  const float* x     = (const float*)d_in[0];
  const float* W_ih0 = (const float*)d_in[1];
  // d_in[2] = W_hh0 (unused: layer-0 state is always zero)
  const float* b_ih0 = (const float*)d_in[3];
  const float* b_hh0 = (const float*)d_in[4];
  const float* W_ihr = (const float*)d_in[5];
  const float* W_hhr = (const float*)d_in[6];
  const float* b_ihr = (const float*)d_in[7];
  const float* b_hhr = (const float*)d_in[8];

  // ws layout (~65 MB): H0 64MB + h2c 1MB + flags + b0s
  char* ws = (char*)d_ws;
  constexpr size_t H0_OFF  = 0;                                   // 256*SLOT bf16 = 64 MB
  constexpr size_t H2B_OFF = H0_OFF + (size_t)Tc * SLOT * 2;      // 4*SLOT bf16 = 1 MB
  constexpr size_t F1_OFF  = H2B_OFF + (size_t)4 * SLOT * 2;      // 8 KB
  constexpr size_t F2_OFF  = F1_OFF + 128 * 16 * 4;               // 8 KB

  unsigned short* H0  = (unsigned short*)(ws + H0_OFF);
  unsigned short* h2c = (unsigned short*)(ws + H2B_OFF);
  float* b0s = (float*)(ws + F2_OFF + 128 * 16 * 4);              // 16 KB, after flags
  int* f1 = (int*)(ws + F1_OFF);
  int* f2 = (int*)(ws + F2_OFF);

  // d_out layout during compute (same byte ranges as rounds 8/9; alias proof carries):
  //   lower half transient: xb (32MB @0) + W0b (4MB @32MB), read only by k_l0.
  //   upper half: h1c [Tc][SLOT] bf16 write-once slots (chunk-reordered WITHIN each
  //   256KB slot — outer ranges identical); out[s] (s>=128) overwrites h1 slots
  //   {2s-256, 2s-255} only after f1>=s+1 and f2>=s order it past all readers.
  unsigned short* xb  = (unsigned short*)d_out;
  unsigned short* W0b = (unsigned short*)d_out + (size_t)Bc * Tc * Ec;
  unsigned short* h1c = (unsigned short*)d_out + (size_t)Tc * SLOT;
  float* out = (float*)d_out;

  int n0 = 4096 * 512;
  k_cvt_bf16<<<n0 / 1024, 256, 0, stream>>>(W_ih0, W0b, n0);
  int nx = Bc * Tc * Ec;
  k_cvt_bf16<<<nx / 1024, 256, 0, stream>>>(x, xb, nx);
  k_prep_small<<<2048, 256, 0, stream>>>(b_ih0, b_hh0, b0s, h2c, f1, f2);
  k_l0<<<dim3(1024, 16), 512, 0, stream>>>(xb, W0b, b0s, H0);

  // PLAIN launch (not cooperative): k_rec uses only flag-based sync, no grid.sync.
  // Co-residency is structural: 128KB LDS/WG caps occupancy at 1 WG/CU, grid = 256
  // = #CUs, launched on an idle stream -> all 256 WGs resident simultaneously.
  // (hipLaunchCooperativeKernel silently failed at blockDim=256 in rounds 4/10.)
  k_rec<<<dim3(256), dim3(256), 0, stream>>>(H0, W_ihr, W_hhr, b_ihr, b_hhr,
                                             h1c, h2c, f1, f2, out);
}

// Round 12
// 6069.576 us; speedup vs baseline: 1.6546x; 1.0216x over previous
//
#include <hip/hip_runtime.h>

static constexpr int Bc = 128;   // batch
static constexpr int Tc = 256;   // timesteps
static constexpr int Ec = 512;   // input embed
static constexpr int Hc = 1024;  // hidden
static constexpr int SLOT = Bc * Hc;  // one h-state tile (elems)
// chunked h-state layout: [slot][chunk(128)][row(128)][col(8)] bf16
// elem addr (ushorts, within slot) = chunk*1024 + row*8 + col ; chunk = globalcol>>3

using bf16x8 = __attribute__((ext_vector_type(8))) short;
using f32x4  = __attribute__((ext_vector_type(4))) float;

__device__ __forceinline__ unsigned short f2bf(float f) {
  unsigned int u = __float_as_uint(f);
  u += 0x7FFFu + ((u >> 16) & 1u);
  return (unsigned short)(u >> 16);
}
__device__ __forceinline__ float sigm(float x) { return 1.0f / (1.0f + __expf(-x)); }
// fast tanh via exp: exact at saturation (exp->inf => 1), ~1e-7 rel error otherwise
__device__ __forceinline__ float ftanh(float x) { return 1.0f - 2.0f / (__expf(2.0f * x) + 1.0f); }

#define MFMA16(A, Bf, C) __builtin_amdgcn_mfma_f32_16x16x32_bf16((A), (Bf), (C), 0, 0, 0)

// ---- sync primitives: UNCHANGED from rounds 9/11 (proven) ----
__device__ __forceinline__ void poll_rlx(const int* p, int tgt) {
  while (__hip_atomic_load(p, __ATOMIC_RELAXED, __HIP_MEMORY_SCOPE_AGENT) < tgt)
    __builtin_amdgcn_s_sleep(1);
}
__device__ __forceinline__ void sig(int* p, int v) {
  __hip_atomic_store(p, v, __ATOMIC_RELAXED, __HIP_MEMORY_SCOPE_AGENT);
}
__device__ __forceinline__ void stg_c(unsigned short* p, unsigned short v) {
  __hip_atomic_store(p, v, __ATOMIC_RELAXED, __HIP_MEMORY_SCOPE_AGENT);
}

// ----------------- prep kernels -----------------
__global__ void k_cvt_bf16(const float* __restrict__ src, unsigned short* __restrict__ dst, int n) {
  int i = (blockIdx.x * blockDim.x + threadIdx.x) * 4;
  if (i + 3 < n) {
    f32x4 v = *(const f32x4*)(src + i);
    *(ushort4*)(dst + i) = make_ushort4(f2bf(v[0]), f2bf(v[1]), f2bf(v[2]), f2bf(v[3]));
  }
}

__global__ void k_prep_small(const float* __restrict__ bih0, const float* __restrict__ bhh0,
                             float* __restrict__ b0s,
                             unsigned short* __restrict__ h2c,     // [4][SLOT]
                             int* __restrict__ f1, int* __restrict__ f2) {
  int i = blockIdx.x * blockDim.x + threadIdx.x;  // grid covers 4*SLOT = 524288
  if (i < 4096) b0s[i] = bih0[i] + bhh0[i];
  h2c[i] = 0;
  if (i < 128 * 16) { f1[i] = 0; f2[i] = 0; }
}

// ----------------- layer-0 bulk GEMM (no recurrence; f-gate dead) -----------------
// writes H0 in CHUNKED layout
__global__ __launch_bounds__(512, 1) void k_l0(
    const unsigned short* __restrict__ xb, const unsigned short* __restrict__ W0,
    const float* __restrict__ b0s, unsigned short* __restrict__ H0)
{
  const int tid = threadIdx.x;
  const int lane = tid & 63, wid = tid >> 6;
  const int wM = wid >> 2, wN = wid & 3;           // 8 waves: 2(M) x 4(N)
  const int rowbase = blockIdx.x * 32 + wM * 16;
  const int jbase   = blockIdx.y * 64 + wN * 16;
  const int ri = lane & 15, kg = lane >> 4;

  const int r = rowbase + ri;
  const int t = r >> 7, b = r & (Bc - 1);
  const unsigned short* arow = xb + ((size_t)b * Tc + t) * Ec + kg * 8;

  const unsigned short* w0r = W0 + ((size_t)(0 * Hc + jbase + ri)) * Ec + kg * 8;
  const unsigned short* w2r = W0 + ((size_t)(2 * Hc + jbase + ri)) * Ec + kg * 8;
  const unsigned short* w3r = W0 + ((size_t)(3 * Hc + jbase + ri)) * Ec + kg * 8;

  f32x4 ai = {0,0,0,0}, ag = {0,0,0,0}, ao = {0,0,0,0};
#pragma unroll
  for (int kk = 0; kk < Ec / 32; ++kk) {
    bf16x8 a = *(const bf16x8*)(arow + kk * 32);
    ai = MFMA16(a, *(const bf16x8*)(w0r + kk * 32), ai);
    ag = MFMA16(a, *(const bf16x8*)(w2r + kk * 32), ag);
    ao = MFMA16(a, *(const bf16x8*)(w3r + kk * 32), ao);
  }
  const int j = jbase + ri;
  const float bi = b0s[j], bg = b0s[2 * Hc + j], bo = b0s[3 * Hc + j];
#pragma unroll
  for (int q = 0; q < 4; ++q) {
    const int rr = rowbase + kg * 4 + q;
    float c = sigm(ai[q] + bi) * ftanh(ag[q] + bg);
    float h = sigm(ao[q] + bo) * ftanh(c);
    // chunked store: slot = rr>>7, row = rr&127, chunk = j>>3, col = j&7
    H0[(size_t)(rr >> 7) * SLOT + (size_t)(j >> 3) * 1024 + (size_t)(rr & 127) * 8 + (j & 7)] = f2bf(h);
  }
}

// ----------------- recurrent kernel: cross-step software pipelining -----------------
// 256 WGs x 256 thr (4 waves), 1 WG/CU, PLAIN launch (co-residency structural:
// 128KB LDS caps 1 WG/CU, grid=256=#CUs). WGs 0..127: layer1; 128..255: layer2.
// NEW vs r11: the dependency-FREE half of the NEXT step (layer1: H0(p+1); layer2:
// h1(s+1) cross-half) and layer2's out-stores are computed in the TAIL after the
// signal — off the inter-WG critical chain. The f-chain serial segment shrinks to
// detect -> gated/own half -> epilogue -> drain -> signal.
__global__ __launch_bounds__(256, 1) void k_rec(
    const unsigned short* H0,                        // [256][SLOT] chunked (ws)
    const float* __restrict__ Wih, const float* __restrict__ Whh,  // [2][4096][1024] f32
    const float* __restrict__ bih, const float* __restrict__ bhh,  // [2][4096] f32
    unsigned short* h1c,                             // [Tc][SLOT] chunked (d_out upper half)
    unsigned short* h2c,                             // [4][SLOT] chunked (ws)
    int* f1, int* f2,                                // [128] slots x 16 ints (64B stride)
    float* out)                                      // [Tc][Bc][Hc] f32 (d_out)
{
  __shared__ unsigned short Wlds[2 * 64 * 64 * 8];   // 128 KiB: [tile][kstep][lane][8]
  const int tid = threadIdx.x;
  const int lane = tid & 63, wid = tid >> 6;         // 4 waves
  const int bid = blockIdx.x;
  const int layer = bid >> 7;
  const int w = bid & 127;
  const int j0 = w * 8;
  const int ri = lane & 15, kg = lane >> 4;

  // ---- prologue: weights fp32 -> bf16 into LDS, fragment-major (unchanged) ----
  const size_t lw = (size_t)layer * 4096 * 1024;
  for (int s = tid; s < 2 * 64 * 64; s += 256) {
    const int l   = s & 63;
    const int kkg = (s >> 6) & 63;
    const int t   = s >> 12;
    const int rr  = l & 15;
    const int gate = t * 2 + (rr >> 3);
    const int R = gate * 1024 + j0 + (rr & 7);
    const int k = kkg * 32 + (l >> 4) * 8;
    const float* src = (k < 1024) ? (Wih + lw + (size_t)R * 1024 + k)
                                  : (Whh + lw + (size_t)R * 1024 + (k - 1024));
    f32x4 v0 = *(const f32x4*)src;
    f32x4 v1 = *(const f32x4*)(src + 4);
    ushort4* d = (ushort4*)(Wlds + (size_t)s * 8);
    d[0] = make_ushort4(f2bf(v0[0]), f2bf(v0[1]), f2bf(v0[2]), f2bf(v0[3]));
    d[1] = make_ushort4(f2bf(v1[0]), f2bf(v1[1]), f2bf(v1[2]), f2bf(v1[3]));
  }

  const int jme = j0 + (ri & 7);
  const int g0 = (ri < 8) ? 0 : 1;                  // tile0: i | f
  const int g1 = (ri < 8) ? 2 : 3;                  // tile1: g | o
  const float bias0 = bih[layer * 4096 + g0 * 1024 + jme] + bhh[layer * 4096 + g0 * 1024 + jme];
  const float bias1 = bih[layer * 4096 + g1 * 1024 + jme] + bhh[layer * 4096 + g1 * 1024 + jme];

  float c0[4]  = {0.f, 0.f, 0.f, 0.f};              // c-state rows wid*32 + kg*4+q
  float c1s[4] = {0.f, 0.f, 0.f, 0.f};              // c-state rows +16

  const unsigned short* lds0 = Wlds + (size_t)lane * 8;
  const unsigned short* lds1 = Wlds + (size_t)64 * 64 * 8 + (size_t)lane * 8;
  // chunked A-fragment per-lane base: chunk = kk*4+kg, row = wid*32+ri (+16 hi)
  const int abase = kg * 1024 + (wid * 32 + ri) * 8;
  const bool lo = (ri < 8);

  f32x4 acc00, acc01, acc10, acc11;
#define ZERO4() { acc00 = (f32x4){0,0,0,0}; acc01 = (f32x4){0,0,0,0}; \
                  acc10 = (f32x4){0,0,0,0}; acc11 = (f32x4){0,0,0,0}; }

#define HALF_MM4(Abase, LDSOFF)                                             \
  {                                                                         \
    const unsigned short* ap_ = (Abase) + abase;                            \
    _Pragma("unroll")                                                       \
    for (int kk = 0; kk < 32; ++kk) {                                       \
      bf16x8 b0 = *(const bf16x8*)(lds0 + (LDSOFF) + kk * 512);             \
      bf16x8 b1 = *(const bf16x8*)(lds1 + (LDSOFF) + kk * 512);             \
      bf16x8 vlo = *(const bf16x8*)(ap_ + kk * 4096);                       \
      bf16x8 vhi = *(const bf16x8*)(ap_ + kk * 4096 + 128);                 \
      acc00 = MFMA16(vlo, b0, acc00);                                       \
      acc01 = MFMA16(vlo, b1, acc01);                                       \
      acc10 = MFMA16(vhi, b0, acc10);                                       \
      acc11 = MFMA16(vhi, b1, acc11);                                       \
    }                                                                       \
  }

#define CELL4(accA, accB, cre, hnarr)                                       \
  _Pragma("unroll")                                                         \
  for (int q = 0; q < 4; ++q) {                                             \
    float x0 = accA[q] + bias0;                                             \
    float x1 = accB[q] + bias1;                                             \
    float p0 = __shfl_xor(x0, 8);                                           \
    float p1 = __shfl_xor(x1, 8);                                           \
    float gi = lo ? x0 : p0;                                                \
    float gf = lo ? p0 : x0;                                                \
    float gg = lo ? x1 : p1;                                                \
    float go = lo ? p1 : x1;                                                \
    float cn = sigm(gf) * cre[q] + sigm(gi) * ftanh(gg);                    \
    hnarr[q] = sigm(go) * ftanh(cn);                                        \
    cre[q] = cn;                                                            \
  }

  __syncthreads();                                  // Wlds ready

  if (layer == 0) {
    // ---------------- layer 1: h1(p) = cell(H0(p), h1(p-1)), pipelined ----------------
    ZERO4()
    HALF_MM4(H0, 0)                                 // free half for p=0 (tail-style prologue)
    for (int p = 0; p < Tc; ++p) {
      // critical chain: detect f1 -> gated half -> epilogue -> drain -> signal
      if (tid < 128 && p >= 1) poll_rlx(f1 + tid * 16, p);
      __syncthreads();
      if (p >= 1) {
        HALF_MM4(h1c + (size_t)(p - 1) * SLOT, 32 * 512)
      }
      float hn0[4], hn1[4];
      CELL4(acc00, acc01, c0, hn0)
      CELL4(acc10, acc11, c1s, hn1)
      if (lo) {
        unsigned short* hb = h1c + (size_t)p * SLOT + (size_t)w * 1024 + (ri & 7);
#pragma unroll
        for (int q = 0; q < 4; ++q) {
          const int r0 = wid * 32 + kg * 4 + q;
          stg_c(hb + (size_t)r0 * 8, f2bf(hn0[q]));
          stg_c(hb + (size_t)(r0 + 16) * 8, f2bf(hn1[q]));
        }
      }
      __syncthreads();                              // pre-barrier vmcnt(0): stores ACKed at L3
      if (tid == 0) sig(f1 + w * 16, p + 1);
      // tail (off-chain): free half of p+1 from H0 (always available)
      if (p + 1 < Tc) {
        ZERO4()
        HALF_MM4(H0 + (size_t)(p + 1) * SLOT, 0)
      }
    }
  } else {
    // ---------------- layer 2: h2(s) = cell(h1(s), h2(s-1)), pipelined ----------------
    // prologue: cross half for s=0 (wait h1(0))
    if (tid < 128) poll_rlx(f1 + tid * 16, 1);
    __syncthreads();
    ZERO4()
    HALF_MM4(h1c, 0)
    float hnp[8]; bool have_out = false;            // deferred out[s-1] values
    int sprev = 0;
    for (int s = 0; s < Tc; ++s) {
      // critical chain: detect f2 -> fence -> own half -> epilogue -> drain -> signal
      if (tid < 128 && s >= 1) poll_rlx(f2 + tid * 16, s);
      __syncthreads();
      __builtin_amdgcn_fence(__ATOMIC_ACQUIRE, "agent");
      HALF_MM4(h2c + (size_t)((s - 1) & 3) * SLOT, 32 * 512)  // s=0: slot 3 is zeros
      float hn0[4], hn1[4];
      CELL4(acc00, acc01, c0, hn0)
      CELL4(acc10, acc11, c1s, hn1)
      if (lo) {
        unsigned short* hb = h2c + (size_t)(s & 3) * SLOT + (size_t)w * 1024 + (ri & 7);
#pragma unroll
        for (int q = 0; q < 4; ++q) {
          const int r0 = wid * 32 + kg * 4 + q;
          stg_c(hb + (size_t)r0 * 8, f2bf(hn0[q]));
          stg_c(hb + (size_t)(r0 + 16) * 8, f2bf(hn1[q]));
        }
      }
      __syncthreads();                              // drains h2 stg_c stores
      if (tid == 0) sig(f2 + w * 16, s + 1);
      // ---- tail (off-chain): out stores for s, then cross half for s+1 ----
      if (lo) {
        float* po = out + (size_t)s * SLOT;
#pragma unroll
        for (int q = 0; q < 4; ++q) {
          const int r0 = wid * 32 + kg * 4 + q;
          po[(size_t)r0 * Hc + jme] = hn0[q];
          po[(size_t)(r0 + 16) * Hc + jme] = hn1[q];
        }
      }
      if (s + 1 < Tc) {
        if (tid < 128) poll_rlx(f1 + tid * 16, s + 2);   // layer-1 runs ahead: cheap
        __syncthreads();
        ZERO4()
        HALF_MM4(h1c + (size_t)(s + 1) * SLOT, 0)
      }
      (void)hnp; (void)have_out; (void)sprev;
    }
  }
}

// ----------------- launcher -----------------
extern "C" void kernel_launch(void* const* d_in, const int* in_sizes, int n_in,
                              void* d_out, int out_size, void* d_ws, size_t ws_size,
                              hipStream_t stream) {
  const float* x     = (const float*)d_in[0];
  const float* W_ih0 = (const float*)d_in[1];
  // d_in[2] = W_hh0 (unused: layer-0 state is always zero)
  const float* b_ih0 = (const float*)d_in[3];
  const float* b_hh0 = (const float*)d_in[4];
  const float* W_ihr = (const float*)d_in[5];
  const float* W_hhr = (const float*)d_in[6];
  const float* b_ihr = (const float*)d_in[7];
  const float* b_hhr = (const float*)d_in[8];

  // ws layout (~65 MB): H0 64MB + h2c 1MB + flags + b0s
  char* ws = (char*)d_ws;
  constexpr size_t H0_OFF  = 0;                                   // 256*SLOT bf16 = 64 MB
  constexpr size_t H2B_OFF = H0_OFF + (size_t)Tc * SLOT * 2;      // 4*SLOT bf16 = 1 MB
  constexpr size_t F1_OFF  = H2B_OFF + (size_t)4 * SLOT * 2;      // 8 KB
  constexpr size_t F2_OFF  = F1_OFF + 128 * 16 * 4;               // 8 KB

  unsigned short* H0  = (unsigned short*)(ws + H0_OFF);
  unsigned short* h2c = (unsigned short*)(ws + H2B_OFF);
  float* b0s = (float*)(ws + F2_OFF + 128 * 16 * 4);              // 16 KB, after flags
  int* f1 = (int*)(ws + F1_OFF);
  int* f2 = (int*)(ws + F2_OFF);

  // d_out layout during compute (same byte ranges as rounds 8-11; alias proof carries,
  // re-derived under the tail-placed out stores incl. s=255):
  //   lower half transient: xb (32MB @0) + W0b (4MB @32MB), read only by k_l0.
  //   upper half: h1c [Tc][SLOT] bf16 write-once slots; out[s] (s>=128) overwrites
  //   h1 slots {2s-256, 2s-255} only after f2>=s and (via cross-half gating) f1-ordering
  //   place it past all readers of those slots.
  unsigned short* xb  = (unsigned short*)d_out;
  unsigned short* W0b = (unsigned short*)d_out + (size_t)Bc * Tc * Ec;
  unsigned short* h1c = (unsigned short*)d_out + (size_t)Tc * SLOT;
  float* out = (float*)d_out;

  int n0 = 4096 * 512;
  k_cvt_bf16<<<n0 / 1024, 256, 0, stream>>>(W_ih0, W0b, n0);
  int nx = Bc * Tc * Ec;
  k_cvt_bf16<<<nx / 1024, 256, 0, stream>>>(x, xb, nx);
  k_prep_small<<<2048, 256, 0, stream>>>(b_ih0, b_hh0, b0s, h2c, f1, f2);
  k_l0<<<dim3(1024, 16), 512, 0, stream>>>(xb, W0b, b0s, H0);

  // PLAIN launch (not cooperative): flag-based sync only, no grid.sync; co-residency
  // structural (128KB LDS -> 1 WG/CU, grid = 256 = #CUs).
  k_rec<<<dim3(256), dim3(256), 0, stream>>>(H0, W_ihr, W_hhr, b_ihr, b_hhr,
                                             h1c, h2c, f1, f2, out);
}

// Round 13
// 4916.396 us; speedup vs baseline: 2.0428x; 1.2346x over previous
//
#include <hip/hip_runtime.h>

static constexpr int Bc = 128;   // batch
static constexpr int Tc = 256;   // timesteps
static constexpr int Ec = 512;   // input embed
static constexpr int Hc = 1024;  // hidden
static constexpr int SLOT = Bc * Hc;  // one h-state tile (elems)
// chunked h-state layout: [slot][chunk(128)][row(128)][col(8)] bf16
// elem addr (ushorts, within slot) = chunk*1024 + row*8 + col ; chunk = globalcol>>3

using bf16x8 = __attribute__((ext_vector_type(8))) short;
using f32x4  = __attribute__((ext_vector_type(4))) float;

__device__ __forceinline__ unsigned short f2bf(float f) {
  unsigned int u = __float_as_uint(f);
  u += 0x7FFFu + ((u >> 16) & 1u);
  return (unsigned short)(u >> 16);
}
__device__ __forceinline__ float sigm(float x) { return 1.0f / (1.0f + __expf(-x)); }
__device__ __forceinline__ float ftanh(float x) { return 1.0f - 2.0f / (__expf(2.0f * x) + 1.0f); }

#define MFMA16(A, Bf, C) __builtin_amdgcn_mfma_f32_16x16x32_bf16((A), (Bf), (C), 0, 0, 0)

// ---- sync primitives: UNCHANGED (proven r9/r11/r12) ----
__device__ __forceinline__ void poll_rlx(const int* p, int tgt) {
  while (__hip_atomic_load(p, __ATOMIC_RELAXED, __HIP_MEMORY_SCOPE_AGENT) < tgt)
    __builtin_amdgcn_s_sleep(1);
}
__device__ __forceinline__ void sig(int* p, int v) {
  __hip_atomic_store(p, v, __ATOMIC_RELAXED, __HIP_MEMORY_SCOPE_AGENT);
}
__device__ __forceinline__ void stg_c(unsigned short* p, unsigned short v) {
  __hip_atomic_store(p, v, __ATOMIC_RELAXED, __HIP_MEMORY_SCOPE_AGENT);
}

// ----------------- prep kernels (unchanged) -----------------
__global__ void k_cvt_bf16(const float* __restrict__ src, unsigned short* __restrict__ dst, int n) {
  int i = (blockIdx.x * blockDim.x + threadIdx.x) * 4;
  if (i + 3 < n) {
    f32x4 v = *(const f32x4*)(src + i);
    *(ushort4*)(dst + i) = make_ushort4(f2bf(v[0]), f2bf(v[1]), f2bf(v[2]), f2bf(v[3]));
  }
}

__global__ void k_prep_small(const float* __restrict__ bih0, const float* __restrict__ bhh0,
                             float* __restrict__ b0s,
                             unsigned short* __restrict__ h2c,     // [4][SLOT]
                             int* __restrict__ f1, int* __restrict__ f2) {
  int i = blockIdx.x * blockDim.x + threadIdx.x;  // grid covers 4*SLOT = 524288
  if (i < 4096) b0s[i] = bih0[i] + bhh0[i];
  h2c[i] = 0;
  if (i < 128 * 16) { f1[i] = 0; f2[i] = 0; }
}

// ----------------- layer-0 bulk GEMM (unchanged from r12) -----------------
__global__ __launch_bounds__(512, 1) void k_l0(
    const unsigned short* __restrict__ xb, const unsigned short* __restrict__ W0,
    const float* __restrict__ b0s, unsigned short* __restrict__ H0)
{
  const int tid = threadIdx.x;
  const int lane = tid & 63, wid = tid >> 6;
  const int wM = wid >> 2, wN = wid & 3;           // 8 waves: 2(M) x 4(N)
  const int rowbase = blockIdx.x * 32 + wM * 16;
  const int jbase   = blockIdx.y * 64 + wN * 16;
  const int ri = lane & 15, kg = lane >> 4;

  const int r = rowbase + ri;
  const int t = r >> 7, b = r & (Bc - 1);
  const unsigned short* arow = xb + ((size_t)b * Tc + t) * Ec + kg * 8;

  const unsigned short* w0r = W0 + ((size_t)(0 * Hc + jbase + ri)) * Ec + kg * 8;
  const unsigned short* w2r = W0 + ((size_t)(2 * Hc + jbase + ri)) * Ec + kg * 8;
  const unsigned short* w3r = W0 + ((size_t)(3 * Hc + jbase + ri)) * Ec + kg * 8;

  f32x4 ai = {0,0,0,0}, ag = {0,0,0,0}, ao = {0,0,0,0};
#pragma unroll
  for (int kk = 0; kk < Ec / 32; ++kk) {
    bf16x8 a = *(const bf16x8*)(arow + kk * 32);
    ai = MFMA16(a, *(const bf16x8*)(w0r + kk * 32), ai);
    ag = MFMA16(a, *(const bf16x8*)(w2r + kk * 32), ag);
    ao = MFMA16(a, *(const bf16x8*)(w3r + kk * 32), ao);
  }
  const int j = jbase + ri;
  const float bi = b0s[j], bg = b0s[2 * Hc + j], bo = b0s[3 * Hc + j];
#pragma unroll
  for (int q = 0; q < 4; ++q) {
    const int rr = rowbase + kg * 4 + q;
    float c = sigm(ai[q] + bi) * ftanh(ag[q] + bg);
    float h = sigm(ao[q] + bo) * ftanh(c);
    H0[(size_t)(rr >> 7) * SLOT + (size_t)(j >> 3) * 1024 + (size_t)(rr & 127) * 8 + (j & 7)] = f2bf(h);
  }
}

// ----------------- recurrent kernel: wave-specialized producer/consumer -----------------
// 256 WGs x 512 thr (8 waves), 1 WG/CU (144KB LDS), PLAIN launch.
// WGs 0..127: layer1; 128..255: layer2. Waves 0-3 ("free"): compute the dependency-free
// half of step p+1 (layer1: H0(p+1); layer2: cross h1(s+1)) and pass partials via LDS.
// Waves 4-7 ("gated"): critical chain only — detect flag -> PLOAD partial -> gated/own
// half (h1c self / h2c ring) -> cell -> store -> signal. 2 waves/SIMD hide load stalls.
// pbuf single-buffered: gated read in (B1,B2); free write after B2; B1(next) orders.
__global__ __launch_bounds__(512, 1) void k_rec(
    const unsigned short* H0,                        // [256][SLOT] chunked (ws)
    const float* __restrict__ Wih, const float* __restrict__ Whh,  // [2][4096][1024] f32
    const float* __restrict__ bih, const float* __restrict__ bhh,  // [2][4096] f32
    unsigned short* h1c,                             // [Tc][SLOT] chunked (d_out upper half)
    unsigned short* h2c,                             // [4][SLOT] chunked (ws)
    int* f1, int* f2,                                // [128] slots x 16 ints (64B stride)
    float* out)                                      // [Tc][Bc][Hc] f32 (d_out)
{
  __shared__ unsigned short Wlds[2 * 64 * 64 * 8];   // 128 KiB: [tile][kstep][lane][8]
  __shared__ float pbuf[4][4][64][4];                // 16 KiB: [m][acc][lane][4] partials
  const int tid = threadIdx.x;
  const int lane = tid & 63, wid = tid >> 6;         // 8 waves
  const int m = wid & 3;                             // M-pair index within role group
  const bool gatedw = (wid >= 4);
  const int bid = blockIdx.x;
  const int layer = bid >> 7;
  const int w = bid & 127;
  const int j0 = w * 8;
  const int ri = lane & 15, kg = lane >> 4;

  // ---- prologue: weights fp32 -> bf16 into LDS, fragment-major (stride 512) ----
  const size_t lw = (size_t)layer * 4096 * 1024;
  for (int s = tid; s < 2 * 64 * 64; s += 512) {
    const int l   = s & 63;
    const int kkg = (s >> 6) & 63;
    const int t   = s >> 12;
    const int rr  = l & 15;
    const int gate = t * 2 + (rr >> 3);
    const int R = gate * 1024 + j0 + (rr & 7);
    const int k = kkg * 32 + (l >> 4) * 8;
    const float* src = (k < 1024) ? (Wih + lw + (size_t)R * 1024 + k)
                                  : (Whh + lw + (size_t)R * 1024 + (k - 1024));
    f32x4 v0 = *(const f32x4*)src;
    f32x4 v1 = *(const f32x4*)(src + 4);
    ushort4* d = (ushort4*)(Wlds + (size_t)s * 8);
    d[0] = make_ushort4(f2bf(v0[0]), f2bf(v0[1]), f2bf(v0[2]), f2bf(v0[3]));
    d[1] = make_ushort4(f2bf(v1[0]), f2bf(v1[1]), f2bf(v1[2]), f2bf(v1[3]));
  }

  const int jme = j0 + (ri & 7);
  const int g0 = (ri < 8) ? 0 : 1;                  // tile0: i | f
  const int g1 = (ri < 8) ? 2 : 3;                  // tile1: g | o
  const float bias0 = bih[layer * 4096 + g0 * 1024 + jme] + bhh[layer * 4096 + g0 * 1024 + jme];
  const float bias1 = bih[layer * 4096 + g1 * 1024 + jme] + bhh[layer * 4096 + g1 * 1024 + jme];

  float c0[4]  = {0.f, 0.f, 0.f, 0.f};              // c-state (gated waves)
  float c1s[4] = {0.f, 0.f, 0.f, 0.f};

  const unsigned short* lds0 = Wlds + (size_t)lane * 8;
  const unsigned short* lds1 = Wlds + (size_t)64 * 64 * 8 + (size_t)lane * 8;
  const int abase = kg * 1024 + (m * 32 + ri) * 8;  // chunked A base (rows m*32+ri, +16)
  const bool lo = (ri < 8);

  f32x4 acc00, acc01, acc10, acc11;
#define ZERO4() { acc00 = (f32x4){0,0,0,0}; acc01 = (f32x4){0,0,0,0}; \
                  acc10 = (f32x4){0,0,0,0}; acc11 = (f32x4){0,0,0,0}; }
#define PLOAD()  { acc00 = *(const f32x4*)&pbuf[m][0][lane][0]; \
                   acc01 = *(const f32x4*)&pbuf[m][1][lane][0]; \
                   acc10 = *(const f32x4*)&pbuf[m][2][lane][0]; \
                   acc11 = *(const f32x4*)&pbuf[m][3][lane][0]; }
#define PWRITE() { *(f32x4*)&pbuf[m][0][lane][0] = acc00; \
                   *(f32x4*)&pbuf[m][1][lane][0] = acc01; \
                   *(f32x4*)&pbuf[m][2][lane][0] = acc10; \
                   *(f32x4*)&pbuf[m][3][lane][0] = acc11; }

#define HALF_MM4(Abase, LDSOFF)                                             \
  {                                                                         \
    const unsigned short* ap_ = (Abase) + abase;                            \
    _Pragma("unroll")                                                       \
    for (int kk = 0; kk < 32; ++kk) {                                       \
      bf16x8 b0 = *(const bf16x8*)(lds0 + (LDSOFF) + kk * 512);             \
      bf16x8 b1 = *(const bf16x8*)(lds1 + (LDSOFF) + kk * 512);             \
      bf16x8 vlo = *(const bf16x8*)(ap_ + kk * 4096);                       \
      bf16x8 vhi = *(const bf16x8*)(ap_ + kk * 4096 + 128);                 \
      acc00 = MFMA16(vlo, b0, acc00);                                       \
      acc01 = MFMA16(vlo, b1, acc01);                                       \
      acc10 = MFMA16(vhi, b0, acc10);                                       \
      acc11 = MFMA16(vhi, b1, acc11);                                       \
    }                                                                       \
  }

#define CELL4(accA, accB, cre, hnarr)                                       \
  _Pragma("unroll")                                                         \
  for (int q = 0; q < 4; ++q) {                                             \
    float x0 = accA[q] + bias0;                                             \
    float x1 = accB[q] + bias1;                                             \
    float p0 = __shfl_xor(x0, 8);                                           \
    float p1 = __shfl_xor(x1, 8);                                           \
    float gi = lo ? x0 : p0;                                                \
    float gf = lo ? p0 : x0;                                                \
    float gg = lo ? x1 : p1;                                                \
    float go = lo ? p1 : x1;                                                \
    float cn = sigm(gf) * cre[q] + sigm(gi) * ftanh(gg);                    \
    hnarr[q] = sigm(go) * ftanh(cn);                                        \
    cre[q] = cn;                                                            \
  }

  __syncthreads();                                  // Wlds ready

  if (layer == 0) {
    // ---------------- layer 1: h1(p) = cell(H0(p), h1(p-1)) ----------------
    // prologue: free waves compute free(0) partial and publish it
    if (!gatedw) { ZERO4() HALF_MM4(H0, 0) PWRITE() }
    __syncthreads();
    for (int p = 0; p < Tc; ++p) {
      // polls before B1 (pollers = gated waves 4-5; B1 releases waves 6-7 too)
      if (tid >= 256 && tid < 384 && p >= 1) poll_rlx(f1 + (tid - 256) * 16, p);
      __syncthreads();                              // B1: flag seen; pbuf(p) readable
      if (gatedw) {
        PLOAD()                                     // free-half partial for p
        if (p >= 1) HALF_MM4(h1c + (size_t)(p - 1) * SLOT, 32 * 512)
        float hn0[4], hn1[4];
        CELL4(acc00, acc01, c0, hn0)
        CELL4(acc10, acc11, c1s, hn1)
        if (lo) {
          unsigned short* hb = h1c + (size_t)p * SLOT + (size_t)w * 1024 + (ri & 7);
#pragma unroll
          for (int q = 0; q < 4; ++q) {
            const int r0 = m * 32 + kg * 4 + q;
            stg_c(hb + (size_t)r0 * 8, f2bf(hn0[q]));
            stg_c(hb + (size_t)(r0 + 16) * 8, f2bf(hn1[q]));
          }
        }
      } else if (p + 1 < Tc) {
        ZERO4() HALF_MM4(H0 + (size_t)(p + 1) * SLOT, 0)   // free half of p+1
      }
      __syncthreads();                              // B2: gated stg_c drained; pbuf consumed
      if (tid == 256) sig(f1 + w * 16, p + 1);
      if (!gatedw && p + 1 < Tc) PWRITE()           // publish free(p+1); B1(p+1) orders
    }
  } else {
    // ---------------- layer 2: h2(s) = cell(h1(s), h2(s-1)) ----------------
    // prologue: free waves need h1(0) -> poll f1>=1, compute cross(0), publish
    if (tid < 128) poll_rlx(f1 + tid * 16, 1);
    __syncthreads();
    if (!gatedw) { ZERO4() HALF_MM4(h1c, 0) PWRITE() }
    __syncthreads();
    for (int s = 0; s < Tc; ++s) {
      // polls before B1: gated on f2(s); free on f1(s+2) for cross(s+1)
      if (tid >= 256 && tid < 384 && s >= 1) poll_rlx(f2 + (tid - 256) * 16, s);
      if (tid < 128 && s + 1 < Tc) poll_rlx(f1 + tid * 16, s + 2);
      __syncthreads();                              // B1
      float hn0[4], hn1[4];
      if (gatedw) {
        __builtin_amdgcn_fence(__ATOMIC_ACQUIRE, "agent");  // h2c ring staleness guard
        PLOAD()                                     // cross(s) partial
        HALF_MM4(h2c + (size_t)((s - 1) & 3) * SLOT, 32 * 512)  // s=0: slot 3 zeros
        CELL4(acc00, acc01, c0, hn0)
        CELL4(acc10, acc11, c1s, hn1)
        if (lo) {
          unsigned short* hb = h2c + (size_t)(s & 3) * SLOT + (size_t)w * 1024 + (ri & 7);
#pragma unroll
          for (int q = 0; q < 4; ++q) {
            const int r0 = m * 32 + kg * 4 + q;
            stg_c(hb + (size_t)r0 * 8, f2bf(hn0[q]));
            stg_c(hb + (size_t)(r0 + 16) * 8, f2bf(hn1[q]));
          }
        }
      } else if (s + 1 < Tc) {
        ZERO4() HALF_MM4(h1c + (size_t)(s + 1) * SLOT, 0)   // cross(s+1)
      }
      __syncthreads();                              // B2
      if (tid == 256) sig(f2 + w * 16, s + 1);
      if (gatedw) {                                 // out stores off-chain (r12-proven order)
        if (lo) {
          float* po = out + (size_t)s * SLOT;
#pragma unroll
          for (int q = 0; q < 4; ++q) {
            const int r0 = m * 32 + kg * 4 + q;
            po[(size_t)r0 * Hc + jme] = hn0[q];
            po[(size_t)(r0 + 16) * Hc + jme] = hn1[q];
          }
        }
      } else if (s + 1 < Tc) {
        PWRITE()                                    // publish cross(s+1)
      }
    }
  }
}

// ----------------- launcher -----------------
extern "C" void kernel_launch(void* const* d_in, const int* in_sizes, int n_in,
                              void* d_out, int out_size, void* d_ws, size_t ws_size,
                              hipStream_t stream) {
  const float* x     = (const float*)d_in[0];
  const float* W_ih0 = (const float*)d_in[1];
  // d_in[2] = W_hh0 (unused: layer-0 state is always zero)
  const float* b_ih0 = (const float*)d_in[3];
  const float* b_hh0 = (const float*)d_in[4];
  const float* W_ihr = (const float*)d_in[5];
  const float* W_hhr = (const float*)d_in[6];
  const float* b_ihr = (const float*)d_in[7];
  const float* b_hhr = (const float*)d_in[8];

  // ws layout (~65 MB): H0 64MB + h2c 1MB + flags + b0s
  char* ws = (char*)d_ws;
  constexpr size_t H0_OFF  = 0;                                   // 256*SLOT bf16 = 64 MB
  constexpr size_t H2B_OFF = H0_OFF + (size_t)Tc * SLOT * 2;      // 4*SLOT bf16 = 1 MB
  constexpr size_t F1_OFF  = H2B_OFF + (size_t)4 * SLOT * 2;      // 8 KB
  constexpr size_t F2_OFF  = F1_OFF + 128 * 16 * 4;               // 8 KB

  unsigned short* H0  = (unsigned short*)(ws + H0_OFF);
  unsigned short* h2c = (unsigned short*)(ws + H2B_OFF);
  float* b0s = (float*)(ws + F2_OFF + 128 * 16 * 4);              // 16 KB, after flags
  int* f1 = (int*)(ws + F1_OFF);
  int* f2 = (int*)(ws + F2_OFF);

  // d_out layout during compute (same byte ranges as rounds 8-12; alias proofs carry):
  //   lower half transient: xb (32MB @0) + W0b (4MB @32MB), read only by k_l0.
  //   upper half: h1c [Tc][SLOT] bf16 write-once slots; out[s] (s>=128) overwrites
  //   h1 slots {2s-256, 2s-255} only after the f1/f2 waits order it past all readers.
  unsigned short* xb  = (unsigned short*)d_out;
  unsigned short* W0b = (unsigned short*)d_out + (size_t)Bc * Tc * Ec;
  unsigned short* h1c = (unsigned short*)d_out + (size_t)Tc * SLOT;
  float* out = (float*)d_out;

  int n0 = 4096 * 512;
  k_cvt_bf16<<<n0 / 1024, 256, 0, stream>>>(W_ih0, W0b, n0);
  int nx = Bc * Tc * Ec;
  k_cvt_bf16<<<nx / 1024, 256, 0, stream>>>(x, xb, nx);
  k_prep_small<<<2048, 256, 0, stream>>>(b_ih0, b_hh0, b0s, h2c, f1, f2);
  k_l0<<<dim3(1024, 16), 512, 0, stream>>>(xb, W0b, b0s, H0);

  // PLAIN launch; co-residency structural (144KB LDS -> 1 WG/CU, grid = 256 = #CUs).
  k_rec<<<dim3(256), dim3(512), 0, stream>>>(H0, W_ihr, W_hhr, b_ihr, b_hhr,
                                             h1c, h2c, f1, f2, out);
}